// Round 14
// baseline (2288.371 us; speedup 1.0000x reference)
//
#include <hip/hip_runtime.h>
#include <stdint.h>

#define TT 256
#define BB 64
#define DD 1024
#define HH 1024
#define G3 3072

typedef unsigned long long ull;
typedef __attribute__((ext_vector_type(8))) short short8;
typedef __attribute__((ext_vector_type(4))) float f32x4;

__device__ __forceinline__ unsigned short f2bf(float f) {
  union { float f; unsigned int i; } v; v.f = f;
  unsigned int x = v.i;
  return (unsigned short)((x + 0x7fffu + ((x >> 16) & 1u)) >> 16);
}
__device__ __forceinline__ float bf2f(unsigned short u) {
  union { unsigned int i; float f; } v; v.i = ((unsigned int)u) << 16; return v.f;
}
__device__ __forceinline__ f32x4 mfma16(short8 a, short8 b, f32x4 c) {
  return __builtin_amdgcn_mfma_f32_16x16x32_bf16(a, b, c, 0, 0, 0);
}
__device__ __forceinline__ void gload_lds16(const void* g, void* l) {
  __builtin_amdgcn_global_load_lds((const __attribute__((address_space(1))) void*)g,
                                   (__attribute__((address_space(3))) void*)l,
                                   16, 0, 0);
}

// ---------------- f32 -> bf16 convert (vectorized) ----------------
__global__ void k_cvt_bf16(const float* __restrict__ in, unsigned short* __restrict__ out, int n4) {
  int i = blockIdx.x * blockDim.x + threadIdx.x;
  int stride = gridDim.x * blockDim.x;
  for (; i < n4; i += stride) {
    float4 v = ((const float4*)in)[i];
    ushort4 o;
    o.x = f2bf(v.x); o.y = f2bf(v.y); o.z = f2bf(v.z); o.w = f2bf(v.w);
    ((ushort4*)out)[i] = o;
  }
}

// ---------------- context projections + bias fold: E[64][3072] ----------------
__global__ __launch_bounds__(256) void k_ctx(
    const unsigned short* __restrict__ cjb, const unsigned short* __restrict__ heb,
    const unsigned short* __restrict__ Wchb, const unsigned short* __restrict__ Wzhb,
    const float* __restrict__ b_ih, const float* __restrict__ b_hh,
    const float* __restrict__ b_ch, const float* __restrict__ b_zh,
    float* __restrict__ E) {
  __shared__ f32x4 red[4][4][64];   // 16 KB
  int n0 = blockIdx.x * 16;         // 192 blocks
  int tid = threadIdx.x;
  int w = tid >> 6, l = tid & 63, lo = l & 15, hi = l >> 4;
  f32x4 acc[4];
#pragma unroll
  for (int r = 0; r < 4; r++) acc[r] = (f32x4){0.f, 0.f, 0.f, 0.f};
#pragma unroll 4
  for (int kk = 0; kk < 16; kk++) {
    int k = w * 512 + kk * 32;
    const unsigned short* Asrc = (k < 1024) ? cjb : heb;
    const unsigned short* Bsrc = (k < 1024) ? Wchb : Wzhb;
    int kw = (k < 1024) ? k : (k - 1024);
    int kof = kw + hi * 8;
    short8 bf = *(const short8*)(Bsrc + (size_t)(n0 + lo) * 1024 + kof);
#pragma unroll
    for (int r = 0; r < 4; r++) {
      short8 af = *(const short8*)(Asrc + (size_t)(r * 16 + lo) * 1024 + kof);
      acc[r] = mfma16(af, bf, acc[r]);
    }
  }
#pragma unroll
  for (int r = 0; r < 4; r++) red[w][r][l] = acc[r];
  __syncthreads();
  f32x4 s = red[0][w][l];
#pragma unroll
  for (int w2 = 1; w2 < 4; w2++) {
    f32x4 p = red[w2][w][l];
    s[0] += p[0]; s[1] += p[1]; s[2] += p[2]; s[3] += p[3];
  }
  int g = n0 + lo;
  float bias = b_ih[g] + b_ch[g] + b_zh[g] + ((g < 2048) ? b_hh[g] : 0.0f);
#pragma unroll
  for (int j = 0; j < 4; j++) {
    int b = w * 16 + hi * 4 + j;
    E[(size_t)b * G3 + g] = s[j] + bias;
  }
}

// ---------------- gi GEMM + E fold: giE[t*64+b][g] = X@Wih^T + E[b][g] (bf16) --------
__global__ __launch_bounds__(256) void k_gemm_gi(
    const unsigned short* __restrict__ Xb,   // [16384][1024] bf16
    const unsigned short* __restrict__ Wb,   // [3072][1024] bf16
    const float* __restrict__ E,             // [64][3072] f32
    unsigned short* __restrict__ gi) {       // [16384][3072] bf16
  __shared__ unsigned short As[128 * 32];
  __shared__ unsigned short Bs[128 * 32];
  int bid = blockIdx.x;
  int mt = bid & 127;
  int nt = bid >> 7;
  int m0 = mt * 128, n0 = nt * 128;
  int tid = threadIdx.x;
  int w = tid >> 6, l = tid & 63, lo = l & 15, hi = l >> 4;
  int wr = w >> 1, wc = w & 1;
  f32x4 acc[4][4];
#pragma unroll
  for (int i = 0; i < 4; i++)
#pragma unroll
    for (int j = 0; j < 4; j++) acc[i][j] = (f32x4){0.f, 0.f, 0.f, 0.f};
  int srow = tid >> 2;
  int scol = (tid & 3) * 8;
  for (int kt = 0; kt < 32; kt++) {
    int k0 = kt * 32;
    __syncthreads();
    gload_lds16(Xb + (size_t)(m0 + srow) * 1024 + k0 + scol, As + srow * 32 + scol);
    gload_lds16(Xb + (size_t)(m0 + 64 + srow) * 1024 + k0 + scol, As + (64 + srow) * 32 + scol);
    gload_lds16(Wb + (size_t)(n0 + srow) * 1024 + k0 + scol, Bs + srow * 32 + scol);
    gload_lds16(Wb + (size_t)(n0 + 64 + srow) * 1024 + k0 + scol, Bs + (64 + srow) * 32 + scol);
    asm volatile("s_waitcnt vmcnt(0)" ::: "memory");
    __syncthreads();
    short8 a[4], b[4];
#pragma unroll
    for (int i = 0; i < 4; i++) a[i] = *(const short8*)(As + (wr * 64 + i * 16 + lo) * 32 + hi * 8);
#pragma unroll
    for (int i = 0; i < 4; i++) b[i] = *(const short8*)(Bs + (wc * 64 + i * 16 + lo) * 32 + hi * 8);
#pragma unroll
    for (int i = 0; i < 4; i++)
#pragma unroll
      for (int j = 0; j < 4; j++) acc[i][j] = mfma16(a[i], b[j], acc[i][j]);
  }
#pragma unroll
  for (int i = 0; i < 4; i++)
#pragma unroll
    for (int j = 0; j < 4; j++)
#pragma unroll
      for (int e = 0; e < 4; e++) {
        int r = m0 + wr * 64 + i * 16 + hi * 4 + e;
        int c = n0 + wc * 64 + j * 16 + lo;
        float v = acc[i][j][e] + E[(size_t)(r & 63) * G3 + c];
        gi[(size_t)r * G3 + c] = f2bf(v);
      }
}

// ---------------- persistent recurrence kernel (v14: write-once + cached reads) --
// R11 structure exactly (2 waves/wg, row-split, no loop barriers, seq poll),
// with ONE change: hbuf has a write-once slot PER STEP (no 2-slot reuse), so
// consumer h-loads are NORMAL CACHED loads — first toucher per XCD fills L2
// from MALL, the other 7 wgs hit L2 (MALL reads 8.4 MB -> ~1 MB/step). Safe:
// addresses are written exactly once (bypass stores, drained before signal)
// and only read after the seq poll observes the signal. Poll is busy-spin.
__global__ __launch_bounds__(128) void k_rnn(
    const unsigned short* __restrict__ giE,   // [256*64][3072] bf16 (incl E)
    const unsigned short* __restrict__ Whhb,  // [3072][1024] bf16
    const float* __restrict__ b_hh,
    const float* __restrict__ h0,
    const int* __restrict__ length,
    unsigned short* __restrict__ hbuf,        // [256][64cb][64row][16] bf16
    float* __restrict__ out,                  // [256][64][1024] f32
    float* __restrict__ hn,                   // [64][1024] f32
    unsigned int* __restrict__ seq) {         // [128] words, 64B-spaced
  extern __shared__ char smem[];
  unsigned short* wlds = (unsigned short*)smem;   // 96 KB [96 frag=kk*3+s][64 lane][8]
  float* h0f = (float*)(smem + 98304);            // [2][16]

  const int cs = blockIdx.x, j0 = cs * 16;
  const int tid = threadIdx.x;
  const int w = tid >> 6, l = tid & 63, lo = l & 15, hi = l >> 4;
  const int rowbase = w * 32;
  const int col = j0 + lo;

  // ---- weight preload: wave w loads kk in [w*16, w*16+16) ----
#pragma unroll
  for (int k2 = 0; k2 < 16; ++k2) {
    int kk = w * 16 + k2;
#pragma unroll
    for (int s = 0; s < 3; ++s) {
      int f = kk * 3 + s;
      short8 v = *(const short8*)(Whhb + (size_t)(s * 1024 + j0 + lo) * 1024 + kk * 32 + hi * 8);
      ((short8*)wlds)[f * 64 + l] = v;
    }
  }
  const float bhhn = b_hh[2048 + col];
  float hA[4], hB[4];
  int lenA[4], lenB[4];
#pragma unroll
  for (int j = 0; j < 4; ++j) {
    int rA = rowbase + hi * 4 + j, rB = rA + 16;
    hA[j] = h0[(size_t)rA * 1024 + col]; lenA[j] = length[rA];
    hB[j] = h0[(size_t)rB * 1024 + col]; lenB[j] = length[rB];
  }
  // ---- publish h(0) into slot 0 (bypass stores -> MALL) ----
  {
    unsigned short* dst = hbuf + (size_t)cs * 1024;
#pragma unroll
    for (int j = 0; j < 4; ++j) {
      unsigned int mA = f2bf(hA[j]), mB = f2bf(hB[j]);
      unsigned int oA = __shfl_xor(mA, 1, 64), oB = __shfl_xor(mB, 1, 64);
      if (!(lo & 1)) {
        int rr = rowbase + hi * 4 + j;
        __hip_atomic_store((unsigned int*)(dst + rr * 16 + lo), mA | (oA << 16),
                           __ATOMIC_RELAXED, __HIP_MEMORY_SCOPE_AGENT);
        __hip_atomic_store((unsigned int*)(dst + (rr + 16) * 16 + lo), mB | (oB << 16),
                           __ATOMIC_RELAXED, __HIP_MEMORY_SCOPE_AGENT);
      }
    }
  }
  if (w == 0 && hi == 0) h0f[lo] = hA[0];   // exact f32 h(0)[0][col]
  __syncthreads();   // init only: wlds + h0f ready
  asm volatile("s_waitcnt vmcnt(0)" ::: "memory");
  if (l == 0)
    __hip_atomic_store(&seq[(cs * 2 + w) * 16], 1u, __ATOMIC_RELAXED, __HIP_MEMORY_SCOPE_AGENT);
  // ---- gir prefetch for t=0: 24 ushort (2 rt x 3 s x 4 j) ----
  unsigned short gir[24];
#pragma unroll
  for (int r2 = 0; r2 < 2; ++r2)
#pragma unroll
    for (int s = 0; s < 3; ++s)
#pragma unroll
      for (int j = 0; j < 4; ++j)
        gir[(r2 * 3 + s) * 4 + j] =
            giE[(size_t)(rowbase + r2 * 16 + hi * 4 + j) * G3 + s * 1024 + col];

#define ISSUE(c, X)                                                                    \
  _Pragma("unroll") for (int k2 = 0; k2 < 8; ++k2) {                                   \
    int kk = (c) * 8 + k2;                                                             \
    size_t cb = (size_t)(kk * 2 + (hi >> 1));                                          \
    X[k2 * 2 + 0] = *(const short8*)(base + (cb * 64 + rowbase + lo) * 16 + (hi & 1) * 8); \
    X[k2 * 2 + 1] = *(const short8*)(base + (cb * 64 + rowbase + 16 + lo) * 16 + (hi & 1) * 8); \
  }
#define CRUNCH(c, X)                                                                   \
  _Pragma("unroll") for (int k2 = 0; k2 < 8; ++k2) {                                   \
    int kk = (c) * 8 + k2;                                                             \
    const short8* wf = ((const short8*)wlds) + (size_t)(kk * 3) * 64 + l;              \
    short8 b0 = wf[0], b1 = wf[64], b2 = wf[128];                                      \
    a00 = mfma16(X[k2 * 2 + 0], b0, a00);                                              \
    a01 = mfma16(X[k2 * 2 + 0], b1, a01);                                              \
    a02 = mfma16(X[k2 * 2 + 0], b2, a02);                                              \
    a10 = mfma16(X[k2 * 2 + 1], b0, a10);                                              \
    a11 = mfma16(X[k2 * 2 + 1], b1, a11);                                              \
    a12 = mfma16(X[k2 * 2 + 1], b2, a12);                                              \
  }

  for (int t = 0; t < TT; ++t) {
    // ---- busy-spin poll: all 128 producer words (2 per lane) ----
    {
      const unsigned int* sp0 = seq + (size_t)(2 * l) * 16;
      const unsigned int* sp1 = sp0 + 16;
      unsigned int tgt = (unsigned int)(t + 1);
      for (;;) {
        unsigned int v0 = __hip_atomic_load(sp0, __ATOMIC_RELAXED, __HIP_MEMORY_SCOPE_AGENT);
        unsigned int v1 = __hip_atomic_load(sp1, __ATOMIC_RELAXED, __HIP_MEMORY_SCOPE_AGENT);
        if (__all((v0 >= tgt) && (v1 >= tgt))) break;
      }
    }
    // compiler fence: normal h loads below must not hoist above the poll
    asm volatile("" ::: "memory");
    __builtin_amdgcn_sched_barrier(0);
    // ---- write-once slot t: normal cached loads (L2-shared per XCD) ----
    const unsigned short* base = hbuf + (size_t)t * 65536;
    f32x4 a00 = {0.f, 0.f, 0.f, 0.f}, a01 = a00, a02 = a00, a10 = a00, a11 = a00, a12 = a00;
    {
      short8 XA[16], XB[16];
      ISSUE(0, XA);
      ISSUE(1, XB);
      CRUNCH(0, XA);
      ISSUE(2, XA);
      CRUNCH(1, XB);
      ISSUE(3, XB);
      CRUNCH(2, XA);
      CRUNCH(3, XB);
    }
    // ---- gates for 8 rows/lane ----
    float h0p = (w == 0) ? __shfl(hA[0], lo, 64) : h0f[(t & 1) * 16 + lo];
    float rA[4], rB[4];
#pragma unroll
    for (int j = 0; j < 4; ++j) {
      float R = a00[j] + bf2f(gir[0 * 4 + j]);
      float I = a01[j] + bf2f(gir[1 * 4 + j]);
      float rg = 1.f / (1.f + __expf(-R));
      float ig = 1.f / (1.f + __expf(-I));
      float nx = bf2f(gir[2 * 4 + j]) + rg * (a02[j] + bhhn);
      nx = fminf(15.f, fmaxf(-15.f, nx));
      float e2 = __expf(2.f * nx);
      float ng = (e2 - 1.f) / (e2 + 1.f);
      float hy = ng + ig * (hA[j] - ng);
      rA[j] = (t < lenA[j]) ? hy : h0p;
    }
#pragma unroll
    for (int j = 0; j < 4; ++j) {
      float R = a10[j] + bf2f(gir[(3 + 0) * 4 + j]);
      float I = a11[j] + bf2f(gir[(3 + 1) * 4 + j]);
      float rg = 1.f / (1.f + __expf(-R));
      float ig = 1.f / (1.f + __expf(-I));
      float nx = bf2f(gir[(3 + 2) * 4 + j]) + rg * (a12[j] + bhhn);
      nx = fminf(15.f, fmaxf(-15.f, nx));
      float e2 = __expf(2.f * nx);
      float ng = (e2 - 1.f) / (e2 + 1.f);
      float hy = ng + ig * (hB[j] - ng);
      rB[j] = (t < lenB[j]) ? hy : h0p;
    }
#pragma unroll
    for (int j = 0; j < 4; ++j) { hA[j] = rA[j]; hB[j] = rB[j]; }
    if (t < TT - 1) {
      // ---- publish h(t+1) into slot t+1 (bypass) + h0f + drain + signal ----
      unsigned short* dst = hbuf + (size_t)(t + 1) * 65536 + (size_t)cs * 1024;
#pragma unroll
      for (int j = 0; j < 4; ++j) {
        unsigned int mA = f2bf(hA[j]), mB = f2bf(hB[j]);
        unsigned int oA = __shfl_xor(mA, 1, 64), oB = __shfl_xor(mB, 1, 64);
        if (!(lo & 1)) {
          int rr = rowbase + hi * 4 + j;
          __hip_atomic_store((unsigned int*)(dst + rr * 16 + lo), mA | (oA << 16),
                             __ATOMIC_RELAXED, __HIP_MEMORY_SCOPE_AGENT);
          __hip_atomic_store((unsigned int*)(dst + (rr + 16) * 16 + lo), mB | (oB << 16),
                             __ATOMIC_RELAXED, __HIP_MEMORY_SCOPE_AGENT);
        }
      }
      if (w == 0 && hi == 0) h0f[((t + 1) & 1) * 16 + lo] = hA[0];
      asm volatile("s_waitcnt vmcnt(0) lgkmcnt(0)" ::: "memory");
      if (l == 0)
        __hip_atomic_store(&seq[(cs * 2 + w) * 16], (unsigned int)(t + 2),
                           __ATOMIC_RELAXED, __HIP_MEMORY_SCOPE_AGENT);
      // ---- off critical path: out(t) stores + gir(t+1) prefetch ----
#pragma unroll
      for (int j = 0; j < 4; ++j) {
        int rr = rowbase + hi * 4 + j;
        out[(size_t)t * (BB * HH) + (size_t)rr * 1024 + col] = rA[j];
        out[(size_t)t * (BB * HH) + (size_t)(rr + 16) * 1024 + col] = rB[j];
      }
      const unsigned short* gb = giE + (size_t)(t + 1) * 64 * G3;
#pragma unroll
      for (int r2 = 0; r2 < 2; ++r2)
#pragma unroll
        for (int s = 0; s < 3; ++s)
#pragma unroll
          for (int j = 0; j < 4; ++j)
            gir[(r2 * 3 + s) * 4 + j] =
                gb[(size_t)(rowbase + r2 * 16 + hi * 4 + j) * G3 + s * 1024 + col];
    } else {
      // ---- tail: out(255) + hn ----
#pragma unroll
      for (int j = 0; j < 4; ++j) {
        int rr = rowbase + hi * 4 + j;
        out[(size_t)t * (BB * HH) + (size_t)rr * 1024 + col] = rA[j];
        out[(size_t)t * (BB * HH) + (size_t)(rr + 16) * 1024 + col] = rB[j];
        hn[(size_t)rr * 1024 + col] = rA[j];
        hn[(size_t)(rr + 16) * 1024 + col] = rB[j];
      }
    }
  }
#undef ISSUE
#undef CRUNCH
}

// ---------------- host ----------------
extern "C" void kernel_launch(void* const* d_in, const int* in_sizes, int n_in,
                              void* d_out, int out_size, void* d_ws, size_t ws_size,
                              hipStream_t stream) {
  const float* input_ = (const float*)d_in[0];
  const int* length   = (const int*)d_in[1];
  const float* h0     = (const float*)d_in[2];
  const float* cj     = (const float*)d_in[3];
  const float* he     = (const float*)d_in[4];
  const float* w_ih   = (const float*)d_in[5];
  const float* w_hh   = (const float*)d_in[6];
  const float* w_ch   = (const float*)d_in[7];
  const float* w_zh   = (const float*)d_in[8];
  const float* b_ih   = (const float*)d_in[9];
  const float* b_hh   = (const float*)d_in[10];
  const float* b_ch   = (const float*)d_in[11];
  const float* b_zh   = (const float*)d_in[12];

  char* ws = (char*)d_ws;
  const size_t OFF_SEQ   = 0;                       // 16 KB: 128 words, 64B-spaced
  const size_t OFF_HBUF  = 16384;                   // 32 MB: [256][131072 B]
  const size_t OFF_XB    = OFF_HBUF + 33554432ull;
  const size_t OFF_WIHB  = OFF_XB + 33554432ull;
  const size_t OFF_WHHB  = OFF_WIHB + 6291456ull;
  const size_t OFF_WCHB  = OFF_WHHB + 6291456ull;
  const size_t OFF_WZHB  = OFF_WCHB + 6291456ull;
  const size_t OFF_CJB   = OFF_WZHB + 6291456ull;
  const size_t OFF_HEB   = OFF_CJB + 131072ull;
  const size_t OFF_E     = OFF_HEB + 131072ull;
  const size_t OFF_GI    = OFF_E + 786432ull;

  unsigned int* seq     = (unsigned int*)(ws + OFF_SEQ);
  unsigned short* hbuf  = (unsigned short*)(ws + OFF_HBUF);
  unsigned short* Xb    = (unsigned short*)(ws + OFF_XB);
  unsigned short* Wihb  = (unsigned short*)(ws + OFF_WIHB);
  unsigned short* Whhb  = (unsigned short*)(ws + OFF_WHHB);
  unsigned short* Wchb  = (unsigned short*)(ws + OFF_WCHB);
  unsigned short* Wzhb  = (unsigned short*)(ws + OFF_WZHB);
  unsigned short* cjb   = (unsigned short*)(ws + OFF_CJB);
  unsigned short* heb   = (unsigned short*)(ws + OFF_HEB);
  float* E              = (float*)(ws + OFF_E);
  unsigned short* gi    = (unsigned short*)(ws + OFF_GI);

  float* out = (float*)d_out;
  float* hn  = out + 16777216;   // T*B*H

  hipFuncSetAttribute((const void*)k_rnn, hipFuncAttributeMaxDynamicSharedMemorySize, 98432);

  hipMemsetAsync(seq, 0, 16384, stream);
  k_cvt_bf16<<<2048, 256, 0, stream>>>(input_, Xb, 16777216 / 4);
  k_cvt_bf16<<<1024, 256, 0, stream>>>(w_ih, Wihb, 3145728 / 4);
  k_cvt_bf16<<<1024, 256, 0, stream>>>(w_hh, Whhb, 3145728 / 4);
  k_cvt_bf16<<<1024, 256, 0, stream>>>(w_ch, Wchb, 3145728 / 4);
  k_cvt_bf16<<<1024, 256, 0, stream>>>(w_zh, Wzhb, 3145728 / 4);
  k_cvt_bf16<<<64, 256, 0, stream>>>(cj, cjb, 65536 / 4);
  k_cvt_bf16<<<64, 256, 0, stream>>>(he, heb, 65536 / 4);
  k_ctx<<<192, 256, 0, stream>>>(cjb, heb, Wchb, Wzhb, b_ih, b_hh, b_ch, b_zh, E);
  k_gemm_gi<<<3072, 256, 0, stream>>>(Xb, Wihb, E, gi);
  k_rnn<<<64, 128, 98432, stream>>>(gi, Whhb, b_hh, h0, length, hbuf, out, hn, seq);
}

// Round 15
// 1645.766 us; speedup vs baseline: 1.3905x; 1.3905x over previous
//
#include <hip/hip_runtime.h>
#include <stdint.h>

#define TT 256
#define BB 64
#define DD 1024
#define HH 1024
#define G3 3072

typedef unsigned long long ull;
typedef __attribute__((ext_vector_type(8))) short short8;
typedef __attribute__((ext_vector_type(4))) float f32x4;

__device__ __forceinline__ unsigned short f2bf(float f) {
  union { float f; unsigned int i; } v; v.f = f;
  unsigned int x = v.i;
  return (unsigned short)((x + 0x7fffu + ((x >> 16) & 1u)) >> 16);
}
__device__ __forceinline__ float bf2f(unsigned short u) {
  union { unsigned int i; float f; } v; v.i = ((unsigned int)u) << 16; return v.f;
}
__device__ __forceinline__ f32x4 mfma16(short8 a, short8 b, f32x4 c) {
  return __builtin_amdgcn_mfma_f32_16x16x32_bf16(a, b, c, 0, 0, 0);
}
__device__ __forceinline__ void gload_lds16(const void* g, void* l) {
  __builtin_amdgcn_global_load_lds((const __attribute__((address_space(1))) void*)g,
                                   (__attribute__((address_space(3))) void*)l,
                                   16, 0, 0);
}
// 16B cache-bypass load (coherent from MALL). Raw asm => caller must provide
// counted vmcnt waits before consuming (rule #18).
__device__ __forceinline__ short8 mall_load16(const unsigned short* p) {
  short8 r;
  asm volatile("global_load_dwordx4 %0, %1, off sc0 sc1" : "=v"(r) : "v"(p));
  return r;
}

// ---------------- f32 -> bf16 convert (vectorized) ----------------
__global__ void k_cvt_bf16(const float* __restrict__ in, unsigned short* __restrict__ out, int n4) {
  int i = blockIdx.x * blockDim.x + threadIdx.x;
  int stride = gridDim.x * blockDim.x;
  for (; i < n4; i += stride) {
    float4 v = ((const float4*)in)[i];
    ushort4 o;
    o.x = f2bf(v.x); o.y = f2bf(v.y); o.z = f2bf(v.z); o.w = f2bf(v.w);
    ((ushort4*)out)[i] = o;
  }
}

// ---------------- context projections + bias fold: E[64][3072] ----------------
__global__ __launch_bounds__(256) void k_ctx(
    const unsigned short* __restrict__ cjb, const unsigned short* __restrict__ heb,
    const unsigned short* __restrict__ Wchb, const unsigned short* __restrict__ Wzhb,
    const float* __restrict__ b_ih, const float* __restrict__ b_hh,
    const float* __restrict__ b_ch, const float* __restrict__ b_zh,
    float* __restrict__ E) {
  __shared__ f32x4 red[4][4][64];   // 16 KB
  int n0 = blockIdx.x * 16;         // 192 blocks
  int tid = threadIdx.x;
  int w = tid >> 6, l = tid & 63, lo = l & 15, hi = l >> 4;
  f32x4 acc[4];
#pragma unroll
  for (int r = 0; r < 4; r++) acc[r] = (f32x4){0.f, 0.f, 0.f, 0.f};
#pragma unroll 4
  for (int kk = 0; kk < 16; kk++) {
    int k = w * 512 + kk * 32;
    const unsigned short* Asrc = (k < 1024) ? cjb : heb;
    const unsigned short* Bsrc = (k < 1024) ? Wchb : Wzhb;
    int kw = (k < 1024) ? k : (k - 1024);
    int kof = kw + hi * 8;
    short8 bf = *(const short8*)(Bsrc + (size_t)(n0 + lo) * 1024 + kof);
#pragma unroll
    for (int r = 0; r < 4; r++) {
      short8 af = *(const short8*)(Asrc + (size_t)(r * 16 + lo) * 1024 + kof);
      acc[r] = mfma16(af, bf, acc[r]);
    }
  }
#pragma unroll
  for (int r = 0; r < 4; r++) red[w][r][l] = acc[r];
  __syncthreads();
  f32x4 s = red[0][w][l];
#pragma unroll
  for (int w2 = 1; w2 < 4; w2++) {
    f32x4 p = red[w2][w][l];
    s[0] += p[0]; s[1] += p[1]; s[2] += p[2]; s[3] += p[3];
  }
  int g = n0 + lo;
  float bias = b_ih[g] + b_ch[g] + b_zh[g] + ((g < 2048) ? b_hh[g] : 0.0f);
#pragma unroll
  for (int j = 0; j < 4; j++) {
    int b = w * 16 + hi * 4 + j;
    E[(size_t)b * G3 + g] = s[j] + bias;
  }
}

// ---------------- gi GEMM + E fold: giE[t*64+b][g] = X@Wih^T + E[b][g] (bf16) --------
__global__ __launch_bounds__(256) void k_gemm_gi(
    const unsigned short* __restrict__ Xb,   // [16384][1024] bf16
    const unsigned short* __restrict__ Wb,   // [3072][1024] bf16
    const float* __restrict__ E,             // [64][3072] f32
    unsigned short* __restrict__ gi) {       // [16384][3072] bf16
  __shared__ unsigned short As[128 * 32];
  __shared__ unsigned short Bs[128 * 32];
  int bid = blockIdx.x;
  int mt = bid & 127;
  int nt = bid >> 7;
  int m0 = mt * 128, n0 = nt * 128;
  int tid = threadIdx.x;
  int w = tid >> 6, l = tid & 63, lo = l & 15, hi = l >> 4;
  int wr = w >> 1, wc = w & 1;
  f32x4 acc[4][4];
#pragma unroll
  for (int i = 0; i < 4; i++)
#pragma unroll
    for (int j = 0; j < 4; j++) acc[i][j] = (f32x4){0.f, 0.f, 0.f, 0.f};
  int srow = tid >> 2;
  int scol = (tid & 3) * 8;
  for (int kt = 0; kt < 32; kt++) {
    int k0 = kt * 32;
    __syncthreads();
    gload_lds16(Xb + (size_t)(m0 + srow) * 1024 + k0 + scol, As + srow * 32 + scol);
    gload_lds16(Xb + (size_t)(m0 + 64 + srow) * 1024 + k0 + scol, As + (64 + srow) * 32 + scol);
    gload_lds16(Wb + (size_t)(n0 + srow) * 1024 + k0 + scol, Bs + srow * 32 + scol);
    gload_lds16(Wb + (size_t)(n0 + 64 + srow) * 1024 + k0 + scol, Bs + (64 + srow) * 32 + scol);
    asm volatile("s_waitcnt vmcnt(0)" ::: "memory");
    __syncthreads();
    short8 a[4], b[4];
#pragma unroll
    for (int i = 0; i < 4; i++) a[i] = *(const short8*)(As + (wr * 64 + i * 16 + lo) * 32 + hi * 8);
#pragma unroll
    for (int i = 0; i < 4; i++) b[i] = *(const short8*)(Bs + (wc * 64 + i * 16 + lo) * 32 + hi * 8);
#pragma unroll
    for (int i = 0; i < 4; i++)
#pragma unroll
      for (int j = 0; j < 4; j++) acc[i][j] = mfma16(a[i], b[j], acc[i][j]);
  }
#pragma unroll
  for (int i = 0; i < 4; i++)
#pragma unroll
    for (int j = 0; j < 4; j++)
#pragma unroll
      for (int e = 0; e < 4; e++) {
        int r = m0 + wr * 64 + i * 16 + hi * 4 + e;
        int c = n0 + wc * 64 + j * 16 + lo;
        float v = acc[i][j][e] + E[(size_t)(r & 63) * G3 + c];
        gi[(size_t)r * G3 + c] = f2bf(v);
      }
}

// ---------------- persistent recurrence kernel (v15: clean poll path) ----------
// Identical to R11 (2 waves/wg, row-split, no loop barriers, 2-slot hbuf,
// bypass h loads with counted waits) EXCEPT the epilogue order: gi(t+1)
// prefetch (girN, double-buffered) and out(t) stores are issued BEFORE the
// pre-signal drain so they share it with the publish acks — the next poll's
// implicit vmcnt(0) then has NO stragglers to drain (R11 paid the cold-HBM
// gi latency + out acks on the observe path every step).
__global__ __launch_bounds__(128) void k_rnn(
    const unsigned short* __restrict__ giE,   // [256*64][3072] bf16 (incl E)
    const unsigned short* __restrict__ Whhb,  // [3072][1024] bf16
    const float* __restrict__ b_hh,
    const float* __restrict__ h0,
    const int* __restrict__ length,
    unsigned short* __restrict__ hbuf,        // [2][64][64][16] ushort
    float* __restrict__ out,                  // [256][64][1024] f32
    float* __restrict__ hn,                   // [64][1024] f32
    unsigned int* __restrict__ seq) {         // [128] words, 64B-spaced
  extern __shared__ char smem[];
  unsigned short* wlds = (unsigned short*)smem;   // 96 KB [96 frag=kk*3+s][64 lane][8]
  float* h0f = (float*)(smem + 98304);            // [2][16]

  const int cs = blockIdx.x, j0 = cs * 16;
  const int tid = threadIdx.x;
  const int w = tid >> 6, l = tid & 63, lo = l & 15, hi = l >> 4;
  const int rowbase = w * 32;
  const int col = j0 + lo;

  // ---- weight preload: wave w loads kk in [w*16, w*16+16) ----
#pragma unroll
  for (int k2 = 0; k2 < 16; ++k2) {
    int kk = w * 16 + k2;
#pragma unroll
    for (int s = 0; s < 3; ++s) {
      int f = kk * 3 + s;
      short8 v = *(const short8*)(Whhb + (size_t)(s * 1024 + j0 + lo) * 1024 + kk * 32 + hi * 8);
      ((short8*)wlds)[f * 64 + l] = v;
    }
  }
  const float bhhn = b_hh[2048 + col];
  float hA[4], hB[4];
  int lenA[4], lenB[4];
#pragma unroll
  for (int j = 0; j < 4; ++j) {
    int rA = rowbase + hi * 4 + j, rB = rA + 16;
    hA[j] = h0[(size_t)rA * 1024 + col]; lenA[j] = length[rA];
    hB[j] = h0[(size_t)rB * 1024 + col]; lenB[j] = length[rB];
  }
  // ---- publish h(0) into slot 0 ----
  {
    unsigned short* dst = hbuf + (size_t)cs * 1024;
#pragma unroll
    for (int j = 0; j < 4; ++j) {
      unsigned int mA = f2bf(hA[j]), mB = f2bf(hB[j]);
      unsigned int oA = __shfl_xor(mA, 1, 64), oB = __shfl_xor(mB, 1, 64);
      if (!(lo & 1)) {
        int rr = rowbase + hi * 4 + j;
        __hip_atomic_store((unsigned int*)(dst + rr * 16 + lo), mA | (oA << 16),
                           __ATOMIC_RELAXED, __HIP_MEMORY_SCOPE_AGENT);
        __hip_atomic_store((unsigned int*)(dst + (rr + 16) * 16 + lo), mB | (oB << 16),
                           __ATOMIC_RELAXED, __HIP_MEMORY_SCOPE_AGENT);
      }
    }
  }
  if (w == 0 && hi == 0) h0f[lo] = hA[0];   // exact f32 h(0)[0][col]
  __syncthreads();   // init only: wlds + h0f ready
  asm volatile("s_waitcnt vmcnt(0)" ::: "memory");
  if (l == 0)
    __hip_atomic_store(&seq[(cs * 2 + w) * 16], 1u, __ATOMIC_RELAXED, __HIP_MEMORY_SCOPE_AGENT);
  // ---- gir prefetch for t=0: 24 ushort (2 rt x 3 s x 4 j) ----
  unsigned short gir[24];
#pragma unroll
  for (int r2 = 0; r2 < 2; ++r2)
#pragma unroll
    for (int s = 0; s < 3; ++s)
#pragma unroll
      for (int j = 0; j < 4; ++j)
        gir[(r2 * 3 + s) * 4 + j] =
            giE[(size_t)(rowbase + r2 * 16 + hi * 4 + j) * G3 + s * 1024 + col];

#define ISSUE(c, X)                                                                    \
  _Pragma("unroll") for (int k2 = 0; k2 < 8; ++k2) {                                   \
    int kk = (c) * 8 + k2;                                                             \
    size_t cb = (size_t)(kk * 2 + (hi >> 1));                                          \
    X[k2 * 2 + 0] = mall_load16(base + (cb * 64 + rowbase + lo) * 16 + (hi & 1) * 8);  \
    X[k2 * 2 + 1] = mall_load16(base + (cb * 64 + rowbase + 16 + lo) * 16 + (hi & 1) * 8); \
  }
#define WAITV(N)                                                                       \
  asm volatile("s_waitcnt vmcnt(" #N ")" ::: "memory");                                \
  __builtin_amdgcn_sched_barrier(0)
#define CRUNCH(c, X)                                                                   \
  _Pragma("unroll") for (int k2 = 0; k2 < 8; ++k2) {                                   \
    int kk = (c) * 8 + k2;                                                             \
    const short8* wf = ((const short8*)wlds) + (size_t)(kk * 3) * 64 + l;              \
    short8 b0 = wf[0], b1 = wf[64], b2 = wf[128];                                      \
    a00 = mfma16(X[k2 * 2 + 0], b0, a00);                                              \
    a01 = mfma16(X[k2 * 2 + 0], b1, a01);                                              \
    a02 = mfma16(X[k2 * 2 + 0], b2, a02);                                              \
    a10 = mfma16(X[k2 * 2 + 1], b0, a10);                                              \
    a11 = mfma16(X[k2 * 2 + 1], b1, a11);                                              \
    a12 = mfma16(X[k2 * 2 + 1], b2, a12);                                              \
  }

  for (int t = 0; t < TT; ++t) {
    // ---- poll all 128 producer words (2 per lane); nothing else in flight ----
    {
      const unsigned int* sp0 = seq + (size_t)(2 * l) * 16;
      const unsigned int* sp1 = sp0 + 16;
      unsigned int tgt = (unsigned int)(t + 1);
      for (;;) {
        unsigned int v0 = __hip_atomic_load(sp0, __ATOMIC_RELAXED, __HIP_MEMORY_SCOPE_AGENT);
        unsigned int v1 = __hip_atomic_load(sp1, __ATOMIC_RELAXED, __HIP_MEMORY_SCOPE_AGENT);
        if (__all((v0 >= tgt) && (v1 >= tgt))) break;
        __builtin_amdgcn_s_sleep(1);
      }
    }
    // ---- chunked A loads + MFMA (full K for 2 row-tiles), counted waits ----
    const unsigned short* base = hbuf + ((size_t)(t & 1) * 64) * 1024;
    f32x4 a00 = {0.f, 0.f, 0.f, 0.f}, a01 = a00, a02 = a00, a10 = a00, a11 = a00, a12 = a00;
    {
      short8 XA[16], XB[16];
      ISSUE(0, XA);        // 16 outstanding
      ISSUE(1, XB);        // 32 outstanding
      WAITV(16);           // chunk 0 landed
      CRUNCH(0, XA);
      ISSUE(2, XA);        // <=32 outstanding
      WAITV(16);           // chunk 1 landed
      CRUNCH(1, XB);
      ISSUE(3, XB);        // <=32 outstanding
      WAITV(16);           // chunk 2 landed
      CRUNCH(2, XA);
      WAITV(0);            // chunk 3 landed
      CRUNCH(3, XB);
    }
    // ---- gates for 8 rows/lane ----
    float h0p = (w == 0) ? __shfl(hA[0], lo, 64) : h0f[(t & 1) * 16 + lo];
    float rA[4], rB[4];
#pragma unroll
    for (int j = 0; j < 4; ++j) {
      float R = a00[j] + bf2f(gir[0 * 4 + j]);
      float I = a01[j] + bf2f(gir[1 * 4 + j]);
      float rg = 1.f / (1.f + __expf(-R));
      float ig = 1.f / (1.f + __expf(-I));
      float nx = bf2f(gir[2 * 4 + j]) + rg * (a02[j] + bhhn);
      nx = fminf(15.f, fmaxf(-15.f, nx));
      float e2 = __expf(2.f * nx);
      float ng = (e2 - 1.f) / (e2 + 1.f);
      float hy = ng + ig * (hA[j] - ng);
      rA[j] = (t < lenA[j]) ? hy : h0p;
    }
#pragma unroll
    for (int j = 0; j < 4; ++j) {
      float R = a10[j] + bf2f(gir[(3 + 0) * 4 + j]);
      float I = a11[j] + bf2f(gir[(3 + 1) * 4 + j]);
      float rg = 1.f / (1.f + __expf(-R));
      float ig = 1.f / (1.f + __expf(-I));
      float nx = bf2f(gir[(3 + 2) * 4 + j]) + rg * (a12[j] + bhhn);
      nx = fminf(15.f, fmaxf(-15.f, nx));
      float e2 = __expf(2.f * nx);
      float ng = (e2 - 1.f) / (e2 + 1.f);
      float hy = ng + ig * (hB[j] - ng);
      rB[j] = (t < lenB[j]) ? hy : h0p;
    }
#pragma unroll
    for (int j = 0; j < 4; ++j) { hA[j] = rA[j]; hB[j] = rB[j]; }
    if (t < TT - 1) {
      // ---- publish h(t+1) first (other wgs' critical path) ----
      unsigned short* dst = hbuf + ((size_t)((t + 1) & 1) * 64 + cs) * 1024;
#pragma unroll
      for (int j = 0; j < 4; ++j) {
        unsigned int mA = f2bf(hA[j]), mB = f2bf(hB[j]);
        unsigned int oA = __shfl_xor(mA, 1, 64), oB = __shfl_xor(mB, 1, 64);
        if (!(lo & 1)) {
          int rr = rowbase + hi * 4 + j;
          __hip_atomic_store((unsigned int*)(dst + rr * 16 + lo), mA | (oA << 16),
                             __ATOMIC_RELAXED, __HIP_MEMORY_SCOPE_AGENT);
          __hip_atomic_store((unsigned int*)(dst + (rr + 16) * 16 + lo), mB | (oB << 16),
                             __ATOMIC_RELAXED, __HIP_MEMORY_SCOPE_AGENT);
        }
      }
      if (w == 0 && hi == 0) h0f[((t + 1) & 1) * 16 + lo] = hA[0];
      // ---- fillers BEFORE the drain: gi(t+1) prefetch + out(t) stores ----
      // (they share the publish drain; next poll finds nothing outstanding)
      unsigned short girN[24];
      {
        const unsigned short* gb = giE + (size_t)(t + 1) * 64 * G3;
#pragma unroll
        for (int r2 = 0; r2 < 2; ++r2)
#pragma unroll
          for (int s = 0; s < 3; ++s)
#pragma unroll
            for (int j = 0; j < 4; ++j)
              girN[(r2 * 3 + s) * 4 + j] =
                  gb[(size_t)(rowbase + r2 * 16 + hi * 4 + j) * G3 + s * 1024 + col];
      }
#pragma unroll
      for (int j = 0; j < 4; ++j) {
        int rr = rowbase + hi * 4 + j;
        out[(size_t)t * (BB * HH) + (size_t)rr * 1024 + col] = rA[j];
        out[(size_t)t * (BB * HH) + (size_t)(rr + 16) * 1024 + col] = rB[j];
      }
      // ---- single drain: publish acks + gi loads + out acks + LDS ----
      asm volatile("s_waitcnt vmcnt(0) lgkmcnt(0)" ::: "memory");
      if (l == 0)
        __hip_atomic_store(&seq[(cs * 2 + w) * 16], (unsigned int)(t + 2),
                           __ATOMIC_RELAXED, __HIP_MEMORY_SCOPE_AGENT);
      // ---- register handoff (loads already drained) ----
#pragma unroll
      for (int q = 0; q < 24; ++q) gir[q] = girN[q];
    } else {
      // ---- tail: out(255) + hn ----
#pragma unroll
      for (int j = 0; j < 4; ++j) {
        int rr = rowbase + hi * 4 + j;
        out[(size_t)t * (BB * HH) + (size_t)rr * 1024 + col] = rA[j];
        out[(size_t)t * (BB * HH) + (size_t)(rr + 16) * 1024 + col] = rB[j];
        hn[(size_t)rr * 1024 + col] = rA[j];
        hn[(size_t)(rr + 16) * 1024 + col] = rB[j];
      }
    }
  }
#undef ISSUE
#undef WAITV
#undef CRUNCH
}

// ---------------- host ----------------
extern "C" void kernel_launch(void* const* d_in, const int* in_sizes, int n_in,
                              void* d_out, int out_size, void* d_ws, size_t ws_size,
                              hipStream_t stream) {
  const float* input_ = (const float*)d_in[0];
  const int* length   = (const int*)d_in[1];
  const float* h0     = (const float*)d_in[2];
  const float* cj     = (const float*)d_in[3];
  const float* he     = (const float*)d_in[4];
  const float* w_ih   = (const float*)d_in[5];
  const float* w_hh   = (const float*)d_in[6];
  const float* w_ch   = (const float*)d_in[7];
  const float* w_zh   = (const float*)d_in[8];
  const float* b_ih   = (const float*)d_in[9];
  const float* b_hh   = (const float*)d_in[10];
  const float* b_ch   = (const float*)d_in[11];
  const float* b_zh   = (const float*)d_in[12];

  char* ws = (char*)d_ws;
  const size_t OFF_SEQ   = 0;               // 16 KB: 128 words, 64B-spaced
  const size_t OFF_HBUF  = 16384;           // 256 KB: [2][64][64][16] ushort
  const size_t OFF_XB    = 524288;
  const size_t OFF_WIHB  = OFF_XB + 33554432ull;
  const size_t OFF_WHHB  = OFF_WIHB + 6291456ull;
  const size_t OFF_WCHB  = OFF_WHHB + 6291456ull;
  const size_t OFF_WZHB  = OFF_WCHB + 6291456ull;
  const size_t OFF_CJB   = OFF_WZHB + 6291456ull;
  const size_t OFF_HEB   = OFF_CJB + 131072ull;
  const size_t OFF_E     = OFF_HEB + 131072ull;
  const size_t OFF_GI    = OFF_E + 786432ull;

  unsigned int* seq     = (unsigned int*)(ws + OFF_SEQ);
  unsigned short* hbuf  = (unsigned short*)(ws + OFF_HBUF);
  unsigned short* Xb    = (unsigned short*)(ws + OFF_XB);
  unsigned short* Wihb  = (unsigned short*)(ws + OFF_WIHB);
  unsigned short* Whhb  = (unsigned short*)(ws + OFF_WHHB);
  unsigned short* Wchb  = (unsigned short*)(ws + OFF_WCHB);
  unsigned short* Wzhb  = (unsigned short*)(ws + OFF_WZHB);
  unsigned short* cjb   = (unsigned short*)(ws + OFF_CJB);
  unsigned short* heb   = (unsigned short*)(ws + OFF_HEB);
  float* E              = (float*)(ws + OFF_E);
  unsigned short* gi    = (unsigned short*)(ws + OFF_GI);

  float* out = (float*)d_out;
  float* hn  = out + 16777216;   // T*B*H

  hipFuncSetAttribute((const void*)k_rnn, hipFuncAttributeMaxDynamicSharedMemorySize, 98432);

  hipMemsetAsync(seq, 0, 16384, stream);
  k_cvt_bf16<<<2048, 256, 0, stream>>>(input_, Xb, 16777216 / 4);
  k_cvt_bf16<<<1024, 256, 0, stream>>>(w_ih, Wihb, 3145728 / 4);
  k_cvt_bf16<<<1024, 256, 0, stream>>>(w_hh, Whhb, 3145728 / 4);
  k_cvt_bf16<<<1024, 256, 0, stream>>>(w_ch, Wchb, 3145728 / 4);
  k_cvt_bf16<<<1024, 256, 0, stream>>>(w_zh, Wzhb, 3145728 / 4);
  k_cvt_bf16<<<64, 256, 0, stream>>>(cj, cjb, 65536 / 4);
  k_cvt_bf16<<<64, 256, 0, stream>>>(he, heb, 65536 / 4);
  k_ctx<<<192, 256, 0, stream>>>(cjb, heb, Wchb, Wzhb, b_ih, b_hh, b_ch, b_zh, E);
  k_gemm_gi<<<3072, 256, 0, stream>>>(Xb, Wihb, E, gi);
  k_rnn<<<64, 128, 98432, stream>>>(gi, Whhb, b_hh, h0, length, hbuf, out, hn, seq);
}

// Round 17
// 1432.866 us; speedup vs baseline: 1.5971x; 1.1486x over previous
//
#include <hip/hip_runtime.h>
#include <stdint.h>

#define TT 256
#define BB 64
#define DD 1024
#define HH 1024
#define G3 3072

typedef unsigned long long ull;
typedef __attribute__((ext_vector_type(8))) short short8;
typedef __attribute__((ext_vector_type(4))) float f32x4;

__device__ __forceinline__ unsigned short f2bf(float f) {
  union { float f; unsigned int i; } v; v.f = f;
  unsigned int x = v.i;
  return (unsigned short)((x + 0x7fffu + ((x >> 16) & 1u)) >> 16);
}
__device__ __forceinline__ float bf2f(unsigned short u) {
  union { unsigned int i; float f; } v; v.i = ((unsigned int)u) << 16; return v.f;
}
__device__ __forceinline__ f32x4 mfma16(short8 a, short8 b, f32x4 c) {
  return __builtin_amdgcn_mfma_f32_16x16x32_bf16(a, b, c, 0, 0, 0);
}
__device__ __forceinline__ void gload_lds16(const void* g, void* l) {
  __builtin_amdgcn_global_load_lds((const __attribute__((address_space(1))) void*)g,
                                   (__attribute__((address_space(3))) void*)l,
                                   16, 0, 0);
}
// 16B cache-bypass load (coherent at MALL). Raw asm: consumed only after the
// explicit counted WAITV chain (rule #18).
__device__ __forceinline__ short8 mall_load16(const unsigned short* p) {
  short8 r;
  asm volatile("global_load_dwordx4 %0, %1, off sc0 sc1" : "=v"(r) : "v"(p));
  return r;
}
// bypass u16 store (MALL-visible cross-XCD); completion tracked by vmcnt.
__device__ __forceinline__ void mall_store_u16(unsigned short* p, unsigned short v) {
  unsigned int vv = v;
  asm volatile("global_store_short %0, %1, off sc0 sc1" :: "v"(p), "v"(vv) : "memory");
}

// ---------------- f32 -> bf16 convert (vectorized) ----------------
__global__ void k_cvt_bf16(const float* __restrict__ in, unsigned short* __restrict__ out, int n4) {
  int i = blockIdx.x * blockDim.x + threadIdx.x;
  int stride = gridDim.x * blockDim.x;
  for (; i < n4; i += stride) {
    float4 v = ((const float4*)in)[i];
    ushort4 o;
    o.x = f2bf(v.x); o.y = f2bf(v.y); o.z = f2bf(v.z); o.w = f2bf(v.w);
    ((ushort4*)out)[i] = o;
  }
}

// ---------------- context projections + bias fold: E[64][3072] ----------------
__global__ __launch_bounds__(256) void k_ctx(
    const unsigned short* __restrict__ cjb, const unsigned short* __restrict__ heb,
    const unsigned short* __restrict__ Wchb, const unsigned short* __restrict__ Wzhb,
    const float* __restrict__ b_ih, const float* __restrict__ b_hh,
    const float* __restrict__ b_ch, const float* __restrict__ b_zh,
    float* __restrict__ E) {
  __shared__ f32x4 red[4][4][64];   // 16 KB
  int n0 = blockIdx.x * 16;         // 192 blocks
  int tid = threadIdx.x;
  int w = tid >> 6, l = tid & 63, lo = l & 15, hi = l >> 4;
  f32x4 acc[4];
#pragma unroll
  for (int r = 0; r < 4; r++) acc[r] = (f32x4){0.f, 0.f, 0.f, 0.f};
#pragma unroll 4
  for (int kk = 0; kk < 16; kk++) {
    int k = w * 512 + kk * 32;
    const unsigned short* Asrc = (k < 1024) ? cjb : heb;
    const unsigned short* Bsrc = (k < 1024) ? Wchb : Wzhb;
    int kw = (k < 1024) ? k : (k - 1024);
    int kof = kw + hi * 8;
    short8 bf = *(const short8*)(Bsrc + (size_t)(n0 + lo) * 1024 + kof);
#pragma unroll
    for (int r = 0; r < 4; r++) {
      short8 af = *(const short8*)(Asrc + (size_t)(r * 16 + lo) * 1024 + kof);
      acc[r] = mfma16(af, bf, acc[r]);
    }
  }
#pragma unroll
  for (int r = 0; r < 4; r++) red[w][r][l] = acc[r];
  __syncthreads();
  f32x4 s = red[0][w][l];
#pragma unroll
  for (int w2 = 1; w2 < 4; w2++) {
    f32x4 p = red[w2][w][l];
    s[0] += p[0]; s[1] += p[1]; s[2] += p[2]; s[3] += p[3];
  }
  int g = n0 + lo;
  float bias = b_ih[g] + b_ch[g] + b_zh[g] + ((g < 2048) ? b_hh[g] : 0.0f);
#pragma unroll
  for (int j = 0; j < 4; j++) {
    int b = w * 16 + hi * 4 + j;
    E[(size_t)b * G3 + g] = s[j] + bias;
  }
}

// ---------------- fused kernel: gi GEMM producers + persistent recurrence ------
// 256 blocks x 256 thr, 96KB+ LDS -> 1 block/CU, all co-resident (rnn blocks
// 0-63 dispatched first; producers never wait on consumers -> deadlock-free).
// Blocks 64-255: 16 gi tiles each (tau = i*192+b, mt-ascending), bypass stores,
// vmcnt(0)+barrier, ready[mt]++ (24 tiles per mt).
// Blocks 0-63: R11 recurrence; gir loads are PLAIN CACHED loads (compiler-
// tracked waits; gi is write-once-per-launch + deterministic so caches can
// only hold identical bytes), gated by ready[] polls with compiler fences.
__global__ __launch_bounds__(256) void k_fused(
    const unsigned short* __restrict__ Xb,    // [16384][1024] bf16
    const unsigned short* __restrict__ Wihb,  // [3072][1024] bf16
    const float* __restrict__ E,              // [64][3072] f32
    unsigned short* __restrict__ gi,          // [16384][3072] bf16 (produced here)
    const unsigned short* __restrict__ Whhb,  // [3072][1024] bf16
    const float* __restrict__ b_hh,
    const float* __restrict__ h0,
    const int* __restrict__ length,
    unsigned short* __restrict__ hbuf,        // [2][64][64][16] ushort
    float* __restrict__ out,                  // [256][64][1024] f32
    float* __restrict__ hn,                   // [64][1024] f32
    unsigned int* __restrict__ seq,           // [128] words, 64B-spaced
    unsigned int* __restrict__ ready) {       // [128] words, 64B-spaced
  extern __shared__ char smem[];
  const int tid = threadIdx.x;

  // ================= GEMM producer role =================
  if (blockIdx.x >= 64) {
    unsigned short* As = (unsigned short*)smem;          // 8 KB
    unsigned short* Bs = As + 128 * 32;                  // 8 KB
    const int b = blockIdx.x - 64;
    const int w = tid >> 6, l = tid & 63, lo = l & 15, hi = l >> 4;
    const int wr = w >> 1, wc = w & 1;
    const int srow = tid >> 2;
    const int scol = (tid & 3) * 8;
    for (int i = 0; i < 16; ++i) {
      int tau = i * 192 + b;
      int mt = tau / 24, nt = tau - mt * 24;
      int m0 = mt * 128, n0 = nt * 128;
      f32x4 acc[4][4];
#pragma unroll
      for (int ii = 0; ii < 4; ii++)
#pragma unroll
        for (int j = 0; j < 4; j++) acc[ii][j] = (f32x4){0.f, 0.f, 0.f, 0.f};
      for (int kt = 0; kt < 32; kt++) {
        int k0 = kt * 32;
        __syncthreads();
        gload_lds16(Xb + (size_t)(m0 + srow) * 1024 + k0 + scol, As + srow * 32 + scol);
        gload_lds16(Xb + (size_t)(m0 + 64 + srow) * 1024 + k0 + scol, As + (64 + srow) * 32 + scol);
        gload_lds16(Wihb + (size_t)(n0 + srow) * 1024 + k0 + scol, Bs + srow * 32 + scol);
        gload_lds16(Wihb + (size_t)(n0 + 64 + srow) * 1024 + k0 + scol, Bs + (64 + srow) * 32 + scol);
        asm volatile("s_waitcnt vmcnt(0)" ::: "memory");
        __syncthreads();
        short8 a[4], bb[4];
#pragma unroll
        for (int ii = 0; ii < 4; ii++) a[ii] = *(const short8*)(As + (wr * 64 + ii * 16 + lo) * 32 + hi * 8);
#pragma unroll
        for (int ii = 0; ii < 4; ii++) bb[ii] = *(const short8*)(Bs + (wc * 64 + ii * 16 + lo) * 32 + hi * 8);
#pragma unroll
        for (int ii = 0; ii < 4; ii++)
#pragma unroll
          for (int j = 0; j < 4; j++) acc[ii][j] = mfma16(a[ii], bb[j], acc[ii][j]);
      }
#pragma unroll
      for (int ii = 0; ii < 4; ii++)
#pragma unroll
        for (int j = 0; j < 4; j++)
#pragma unroll
          for (int e = 0; e < 4; e++) {
            int r = m0 + wr * 64 + ii * 16 + hi * 4 + e;
            int c = n0 + wc * 64 + j * 16 + lo;
            float v = acc[ii][j][e] + E[(size_t)(r & 63) * G3 + c];
            mall_store_u16(gi + (size_t)r * G3 + c, f2bf(v));
          }
      asm volatile("s_waitcnt vmcnt(0)" ::: "memory");
      __syncthreads();   // all waves' stores at MALL
      if (tid == 0)
        __hip_atomic_fetch_add(&ready[mt * 16], 1u, __ATOMIC_RELAXED, __HIP_MEMORY_SCOPE_AGENT);
    }
    return;
  }

  // ================= recurrence role (blocks 0-63) =================
  unsigned short* wlds = (unsigned short*)smem;   // 96 KB [96 frag=kk*3+s][64 lane][8]
  float* h0f = (float*)(smem + 98304);            // [2][16]

  const int cs = blockIdx.x, j0 = cs * 16;
  const int w = tid >> 6, l = tid & 63, lo = l & 15, hi = l >> 4;
  const int rowbase = w * 32;
  const int col = j0 + lo;

  float bhhn = 0.f;
  float hA[4] = {0,0,0,0}, hB[4] = {0,0,0,0};
  int lenA[4] = {0,0,0,0}, lenB[4] = {0,0,0,0};

  if (tid < 128) {
    // weight preload: wave w loads kk in [w*16, w*16+16)
#pragma unroll
    for (int k2 = 0; k2 < 16; ++k2) {
      int kk = w * 16 + k2;
#pragma unroll
      for (int s = 0; s < 3; ++s) {
        int f = kk * 3 + s;
        short8 v = *(const short8*)(Whhb + (size_t)(s * 1024 + j0 + lo) * 1024 + kk * 32 + hi * 8);
        ((short8*)wlds)[f * 64 + l] = v;
      }
    }
    bhhn = b_hh[2048 + col];
#pragma unroll
    for (int j = 0; j < 4; ++j) {
      int rA = rowbase + hi * 4 + j, rB = rA + 16;
      hA[j] = h0[(size_t)rA * 1024 + col]; lenA[j] = length[rA];
      hB[j] = h0[(size_t)rB * 1024 + col]; lenB[j] = length[rB];
    }
    unsigned short* dst = hbuf + (size_t)cs * 1024;
#pragma unroll
    for (int j = 0; j < 4; ++j) {
      unsigned int mA = f2bf(hA[j]), mB = f2bf(hB[j]);
      unsigned int oA = __shfl_xor(mA, 1, 64), oB = __shfl_xor(mB, 1, 64);
      if (!(lo & 1)) {
        int rr = rowbase + hi * 4 + j;
        __hip_atomic_store((unsigned int*)(dst + rr * 16 + lo), mA | (oA << 16),
                           __ATOMIC_RELAXED, __HIP_MEMORY_SCOPE_AGENT);
        __hip_atomic_store((unsigned int*)(dst + (rr + 16) * 16 + lo), mB | (oB << 16),
                           __ATOMIC_RELAXED, __HIP_MEMORY_SCOPE_AGENT);
      }
    }
    if (w == 0 && hi == 0) h0f[lo] = hA[0];
  }
  __syncthreads();          // ALL 256 threads arrive exactly once
  if (tid >= 128) return;   // extra threads exit AFTER the barrier
  asm volatile("s_waitcnt vmcnt(0)" ::: "memory");
  if (l == 0)
    __hip_atomic_store(&seq[(cs * 2 + w) * 16], 1u, __ATOMIC_RELAXED, __HIP_MEMORY_SCOPE_AGENT);

#define POLL_READY(MT)                                                                  \
  {                                                                                     \
    const unsigned int* rp = ready + (size_t)(MT) * 16;                                 \
    for (;;) {                                                                          \
      unsigned int v = __hip_atomic_load(rp, __ATOMIC_RELAXED, __HIP_MEMORY_SCOPE_AGENT);\
      if (v >= 24u) break;                                                              \
      __builtin_amdgcn_s_sleep(1);                                                      \
    }                                                                                   \
    asm volatile("" ::: "memory");                                                      \
    __builtin_amdgcn_sched_barrier(0);                                                  \
  }

  // gir prefetch for t=0 (gi rows 0..63 -> mt 0); PLAIN loads (compiler waits)
  unsigned short gir[24];
  POLL_READY(0);
#pragma unroll
  for (int r2 = 0; r2 < 2; ++r2)
#pragma unroll
    for (int s = 0; s < 3; ++s)
#pragma unroll
      for (int j = 0; j < 4; ++j)
        gir[(r2 * 3 + s) * 4 + j] =
            gi[(size_t)(rowbase + r2 * 16 + hi * 4 + j) * G3 + s * 1024 + col];

#define ISSUE(c, X)                                                                    \
  _Pragma("unroll") for (int k2 = 0; k2 < 8; ++k2) {                                   \
    int kk = (c) * 8 + k2;                                                             \
    size_t cb = (size_t)(kk * 2 + (hi >> 1));                                          \
    X[k2 * 2 + 0] = mall_load16(base + (cb * 64 + rowbase + lo) * 16 + (hi & 1) * 8);  \
    X[k2 * 2 + 1] = mall_load16(base + (cb * 64 + rowbase + 16 + lo) * 16 + (hi & 1) * 8); \
  }
#define WAITV(N)                                                                       \
  asm volatile("s_waitcnt vmcnt(" #N ")" ::: "memory");                                \
  __builtin_amdgcn_sched_barrier(0)
#define CRUNCH(c, X)                                                                   \
  _Pragma("unroll") for (int k2 = 0; k2 < 8; ++k2) {                                   \
    int kk = (c) * 8 + k2;                                                             \
    const short8* wf = ((const short8*)wlds) + (size_t)(kk * 3) * 64 + l;              \
    short8 b0 = wf[0], b1 = wf[64], b2 = wf[128];                                      \
    a00 = mfma16(X[k2 * 2 + 0], b0, a00);                                              \
    a01 = mfma16(X[k2 * 2 + 0], b1, a01);                                              \
    a02 = mfma16(X[k2 * 2 + 0], b2, a02);                                              \
    a10 = mfma16(X[k2 * 2 + 1], b0, a10);                                              \
    a11 = mfma16(X[k2 * 2 + 1], b1, a11);                                              \
    a12 = mfma16(X[k2 * 2 + 1], b2, a12);                                              \
  }

  for (int t = 0; t < TT; ++t) {
    // ---- poll all 128 h producers (2 per lane) ----
    {
      const unsigned int* sp0 = seq + (size_t)(2 * l) * 16;
      const unsigned int* sp1 = sp0 + 16;
      unsigned int tgt = (unsigned int)(t + 1);
      for (;;) {
        unsigned int v0 = __hip_atomic_load(sp0, __ATOMIC_RELAXED, __HIP_MEMORY_SCOPE_AGENT);
        unsigned int v1 = __hip_atomic_load(sp1, __ATOMIC_RELAXED, __HIP_MEMORY_SCOPE_AGENT);
        if (__all((v0 >= tgt) && (v1 >= tgt))) break;
        __builtin_amdgcn_s_sleep(1);
      }
    }
    // ---- chunked A loads + MFMA, counted waits (R11) ----
    const unsigned short* base = hbuf + ((size_t)(t & 1) * 64) * 1024;
    f32x4 a00 = {0.f, 0.f, 0.f, 0.f}, a01 = a00, a02 = a00, a10 = a00, a11 = a00, a12 = a00;
    {
      short8 XA[16], XB[16];
      ISSUE(0, XA);
      ISSUE(1, XB);
      WAITV(16);
      CRUNCH(0, XA);
      ISSUE(2, XA);
      WAITV(16);
      CRUNCH(1, XB);
      ISSUE(3, XB);
      WAITV(16);
      CRUNCH(2, XA);
      WAITV(0);
      CRUNCH(3, XB);
    }
    // ---- gates ----
    float h0p = (w == 0) ? __shfl(hA[0], lo, 64) : h0f[(t & 1) * 16 + lo];
    float rA[4], rB[4];
#pragma unroll
    for (int j = 0; j < 4; ++j) {
      float R = a00[j] + bf2f(gir[0 * 4 + j]);
      float I = a01[j] + bf2f(gir[1 * 4 + j]);
      float rg = 1.f / (1.f + __expf(-R));
      float ig = 1.f / (1.f + __expf(-I));
      float nx = bf2f(gir[2 * 4 + j]) + rg * (a02[j] + bhhn);
      nx = fminf(15.f, fmaxf(-15.f, nx));
      float e2 = __expf(2.f * nx);
      float ng = (e2 - 1.f) / (e2 + 1.f);
      float hy = ng + ig * (hA[j] - ng);
      rA[j] = (t < lenA[j]) ? hy : h0p;
    }
#pragma unroll
    for (int j = 0; j < 4; ++j) {
      float R = a10[j] + bf2f(gir[(3 + 0) * 4 + j]);
      float I = a11[j] + bf2f(gir[(3 + 1) * 4 + j]);
      float rg = 1.f / (1.f + __expf(-R));
      float ig = 1.f / (1.f + __expf(-I));
      float nx = bf2f(gir[(3 + 2) * 4 + j]) + rg * (a12[j] + bhhn);
      nx = fminf(15.f, fmaxf(-15.f, nx));
      float e2 = __expf(2.f * nx);
      float ng = (e2 - 1.f) / (e2 + 1.f);
      float hy = ng + ig * (hB[j] - ng);
      rB[j] = (t < lenB[j]) ? hy : h0p;
    }
#pragma unroll
    for (int j = 0; j < 4; ++j) { hA[j] = rA[j]; hB[j] = rB[j]; }
    if (t < TT - 1) {
      // ---- publish h(t+1) + h0f + drain + signal (R11 order) ----
      unsigned short* dst = hbuf + ((size_t)((t + 1) & 1) * 64 + cs) * 1024;
#pragma unroll
      for (int j = 0; j < 4; ++j) {
        unsigned int mA = f2bf(hA[j]), mB = f2bf(hB[j]);
        unsigned int oA = __shfl_xor(mA, 1, 64), oB = __shfl_xor(mB, 1, 64);
        if (!(lo & 1)) {
          int rr = rowbase + hi * 4 + j;
          __hip_atomic_store((unsigned int*)(dst + rr * 16 + lo), mA | (oA << 16),
                             __ATOMIC_RELAXED, __HIP_MEMORY_SCOPE_AGENT);
          __hip_atomic_store((unsigned int*)(dst + (rr + 16) * 16 + lo), mB | (oB << 16),
                             __ATOMIC_RELAXED, __HIP_MEMORY_SCOPE_AGENT);
        }
      }
      if (w == 0 && hi == 0) h0f[((t + 1) & 1) * 16 + lo] = hA[0];
      asm volatile("s_waitcnt vmcnt(0) lgkmcnt(0)" ::: "memory");
      if (l == 0)
        __hip_atomic_store(&seq[(cs * 2 + w) * 16], (unsigned int)(t + 2),
                           __ATOMIC_RELAXED, __HIP_MEMORY_SCOPE_AGENT);
      // ---- off critical path: out(t), gi readiness, gir(t+1) plain loads ----
#pragma unroll
      for (int j = 0; j < 4; ++j) {
        int rr = rowbase + hi * 4 + j;
        out[(size_t)t * (BB * HH) + (size_t)rr * 1024 + col] = rA[j];
        out[(size_t)t * (BB * HH) + (size_t)(rr + 16) * 1024 + col] = rB[j];
      }
      if (((t + 1) & 1) == 0) { POLL_READY((t + 1) >> 1); }   // new mt every 2 steps
      const unsigned short* gb = gi + (size_t)(t + 1) * 64 * G3;
#pragma unroll
      for (int r2 = 0; r2 < 2; ++r2)
#pragma unroll
        for (int s = 0; s < 3; ++s)
#pragma unroll
          for (int j = 0; j < 4; ++j)
            gir[(r2 * 3 + s) * 4 + j] =
                gb[(size_t)(rowbase + r2 * 16 + hi * 4 + j) * G3 + s * 1024 + col];
    } else {
#pragma unroll
      for (int j = 0; j < 4; ++j) {
        int rr = rowbase + hi * 4 + j;
        out[(size_t)t * (BB * HH) + (size_t)rr * 1024 + col] = rA[j];
        out[(size_t)t * (BB * HH) + (size_t)(rr + 16) * 1024 + col] = rB[j];
        hn[(size_t)rr * 1024 + col] = rA[j];
        hn[(size_t)(rr + 16) * 1024 + col] = rB[j];
      }
    }
  }
#undef ISSUE
#undef WAITV
#undef CRUNCH
#undef POLL_READY
}

// ---------------- host ----------------
extern "C" void kernel_launch(void* const* d_in, const int* in_sizes, int n_in,
                              void* d_out, int out_size, void* d_ws, size_t ws_size,
                              hipStream_t stream) {
  const float* input_ = (const float*)d_in[0];
  const int* length   = (const int*)d_in[1];
  const float* h0     = (const float*)d_in[2];
  const float* cj     = (const float*)d_in[3];
  const float* he     = (const float*)d_in[4];
  const float* w_ih   = (const float*)d_in[5];
  const float* w_hh   = (const float*)d_in[6];
  const float* w_ch   = (const float*)d_in[7];
  const float* w_zh   = (const float*)d_in[8];
  const float* b_ih   = (const float*)d_in[9];
  const float* b_hh   = (const float*)d_in[10];
  const float* b_ch   = (const float*)d_in[11];
  const float* b_zh   = (const float*)d_in[12];

  char* ws = (char*)d_ws;
  const size_t OFF_SEQ   = 0;               // 16 KB region
  const size_t OFF_READY = 16384;           // 8 KB region
  const size_t OFF_HBUF  = 32768;           // 256 KB
  const size_t OFF_XB    = 524288;
  const size_t OFF_WIHB  = OFF_XB + 33554432ull;
  const size_t OFF_WHHB  = OFF_WIHB + 6291456ull;
  const size_t OFF_WCHB  = OFF_WHHB + 6291456ull;
  const size_t OFF_WZHB  = OFF_WCHB + 6291456ull;
  const size_t OFF_CJB   = OFF_WZHB + 6291456ull;
  const size_t OFF_HEB   = OFF_CJB + 131072ull;
  const size_t OFF_E     = OFF_HEB + 131072ull;
  const size_t OFF_GI    = OFF_E + 786432ull;

  unsigned int* seq     = (unsigned int*)(ws + OFF_SEQ);
  unsigned int* ready   = (unsigned int*)(ws + OFF_READY);
  unsigned short* hbuf  = (unsigned short*)(ws + OFF_HBUF);
  unsigned short* Xb    = (unsigned short*)(ws + OFF_XB);
  unsigned short* Wihb  = (unsigned short*)(ws + OFF_WIHB);
  unsigned short* Whhb  = (unsigned short*)(ws + OFF_WHHB);
  unsigned short* Wchb  = (unsigned short*)(ws + OFF_WCHB);
  unsigned short* Wzhb  = (unsigned short*)(ws + OFF_WZHB);
  unsigned short* cjb   = (unsigned short*)(ws + OFF_CJB);
  unsigned short* heb   = (unsigned short*)(ws + OFF_HEB);
  float* E              = (float*)(ws + OFF_E);
  unsigned short* gi    = (unsigned short*)(ws + OFF_GI);

  float* out = (float*)d_out;
  float* hn  = out + 16777216;   // T*B*H

  hipFuncSetAttribute((const void*)k_fused, hipFuncAttributeMaxDynamicSharedMemorySize, 98432);

  hipMemsetAsync(ws, 0, 24576, stream);   // seq + ready
  k_cvt_bf16<<<2048, 256, 0, stream>>>(input_, Xb, 16777216 / 4);
  k_cvt_bf16<<<1024, 256, 0, stream>>>(w_ih, Wihb, 3145728 / 4);
  k_cvt_bf16<<<1024, 256, 0, stream>>>(w_hh, Whhb, 3145728 / 4);
  k_cvt_bf16<<<1024, 256, 0, stream>>>(w_ch, Wchb, 3145728 / 4);
  k_cvt_bf16<<<1024, 256, 0, stream>>>(w_zh, Wzhb, 3145728 / 4);
  k_cvt_bf16<<<64, 256, 0, stream>>>(cj, cjb, 65536 / 4);
  k_cvt_bf16<<<64, 256, 0, stream>>>(he, heb, 65536 / 4);
  k_ctx<<<192, 256, 0, stream>>>(cjb, heb, Wchb, Wzhb, b_ih, b_hh, b_ch, b_zh, E);
  k_fused<<<256, 256, 98432, stream>>>(Xb, Wihb, E, gi, Whhb, b_hh, h0, length,
                                       hbuf, out, hn, seq, ready);
}

// Round 18
// 1432.565 us; speedup vs baseline: 1.5974x; 1.0002x over previous
//
#include <hip/hip_runtime.h>
#include <stdint.h>

#define TT 256
#define BB 64
#define DD 1024
#define HH 1024
#define G3 3072

typedef unsigned long long ull;
typedef __attribute__((ext_vector_type(8))) short short8;
typedef __attribute__((ext_vector_type(4))) float f32x4;

__device__ __forceinline__ unsigned short f2bf(float f) {
  union { float f; unsigned int i; } v; v.f = f;
  unsigned int x = v.i;
  return (unsigned short)((x + 0x7fffu + ((x >> 16) & 1u)) >> 16);
}
__device__ __forceinline__ float bf2f(unsigned short u) {
  union { unsigned int i; float f; } v; v.i = ((unsigned int)u) << 16; return v.f;
}
__device__ __forceinline__ f32x4 mfma16(short8 a, short8 b, f32x4 c) {
  return __builtin_amdgcn_mfma_f32_16x16x32_bf16(a, b, c, 0, 0, 0);
}
__device__ __forceinline__ void gload_lds16(const void* g, void* l) {
  __builtin_amdgcn_global_load_lds((const __attribute__((address_space(1))) void*)g,
                                   (__attribute__((address_space(3))) void*)l,
                                   16, 0, 0);
}
// cache-bypass ops (coherent at MALL). Raw asm loads: consumed only after the
// explicit counted WAITV chain (rule #18).
__device__ __forceinline__ short8 mall_load16(const unsigned short* p) {
  short8 r;
  asm volatile("global_load_dwordx4 %0, %1, off sc0 sc1" : "=v"(r) : "v"(p));
  return r;
}
__device__ __forceinline__ void mall_store16(unsigned short* p, short8 v) {
  asm volatile("global_store_dwordx4 %0, %1, off sc0 sc1" :: "v"(p), "v"(v) : "memory");
}

// ---------------- f32 -> bf16 convert (vectorized) ----------------
__global__ void k_cvt_bf16(const float* __restrict__ in, unsigned short* __restrict__ out, int n4) {
  int i = blockIdx.x * blockDim.x + threadIdx.x;
  int stride = gridDim.x * blockDim.x;
  for (; i < n4; i += stride) {
    float4 v = ((const float4*)in)[i];
    ushort4 o;
    o.x = f2bf(v.x); o.y = f2bf(v.y); o.z = f2bf(v.z); o.w = f2bf(v.w);
    ((ushort4*)out)[i] = o;
  }
}

// ---------------- context projections + bias fold: E[64][3072] ----------------
__global__ __launch_bounds__(256) void k_ctx(
    const unsigned short* __restrict__ cjb, const unsigned short* __restrict__ heb,
    const unsigned short* __restrict__ Wchb, const unsigned short* __restrict__ Wzhb,
    const float* __restrict__ b_ih, const float* __restrict__ b_hh,
    const float* __restrict__ b_ch, const float* __restrict__ b_zh,
    float* __restrict__ E) {
  __shared__ f32x4 red[4][4][64];   // 16 KB
  int n0 = blockIdx.x * 16;         // 192 blocks
  int tid = threadIdx.x;
  int w = tid >> 6, l = tid & 63, lo = l & 15, hi = l >> 4;
  f32x4 acc[4];
#pragma unroll
  for (int r = 0; r < 4; r++) acc[r] = (f32x4){0.f, 0.f, 0.f, 0.f};
#pragma unroll 4
  for (int kk = 0; kk < 16; kk++) {
    int k = w * 512 + kk * 32;
    const unsigned short* Asrc = (k < 1024) ? cjb : heb;
    const unsigned short* Bsrc = (k < 1024) ? Wchb : Wzhb;
    int kw = (k < 1024) ? k : (k - 1024);
    int kof = kw + hi * 8;
    short8 bf = *(const short8*)(Bsrc + (size_t)(n0 + lo) * 1024 + kof);
#pragma unroll
    for (int r = 0; r < 4; r++) {
      short8 af = *(const short8*)(Asrc + (size_t)(r * 16 + lo) * 1024 + kof);
      acc[r] = mfma16(af, bf, acc[r]);
    }
  }
#pragma unroll
  for (int r = 0; r < 4; r++) red[w][r][l] = acc[r];
  __syncthreads();
  f32x4 s = red[0][w][l];
#pragma unroll
  for (int w2 = 1; w2 < 4; w2++) {
    f32x4 p = red[w2][w][l];
    s[0] += p[0]; s[1] += p[1]; s[2] += p[2]; s[3] += p[3];
  }
  int g = n0 + lo;
  float bias = b_ih[g] + b_ch[g] + b_zh[g] + ((g < 2048) ? b_hh[g] : 0.0f);
#pragma unroll
  for (int j = 0; j < 4; j++) {
    int b = w * 16 + hi * 4 + j;
    E[(size_t)b * G3 + g] = s[j] + bias;
  }
}

// ---------------- fused kernel: gi GEMM producers + persistent recurrence ------
// 256 blocks x 256 thr, 96KB+ LDS -> 1 block/CU, all co-resident.
// Blocks 64-255: 16 gi tiles each (tau = i*192+b, mt-ascending). Epilogue:
//   C-tile staged to LDS [128][132] (pad 4 -> 2-way-free banks), then
//   COALESCED 16B bypass stores (8/thread, 2048/tile vs 12288 scalar in R17).
// Blocks 0-63: R11 recurrence; gir via plain cached loads gated by ready[].
__global__ __launch_bounds__(256) void k_fused(
    const unsigned short* __restrict__ Xb,    // [16384][1024] bf16
    const unsigned short* __restrict__ Wihb,  // [3072][1024] bf16
    const float* __restrict__ E,              // [64][3072] f32
    unsigned short* __restrict__ gi,          // [16384][3072] bf16 (produced here)
    const unsigned short* __restrict__ Whhb,  // [3072][1024] bf16
    const float* __restrict__ b_hh,
    const float* __restrict__ h0,
    const int* __restrict__ length,
    unsigned short* __restrict__ hbuf,        // [2][64][64][16] ushort
    float* __restrict__ out,                  // [256][64][1024] f32
    float* __restrict__ hn,                   // [64][1024] f32
    unsigned int* __restrict__ seq,           // [128] words, 64B-spaced
    unsigned int* __restrict__ ready) {       // [128] words, 64B-spaced
  extern __shared__ char smem[];
  const int tid = threadIdx.x;

  // ================= GEMM producer role =================
  if (blockIdx.x >= 64) {
    unsigned short* As = (unsigned short*)smem;          // 8 KB
    unsigned short* Bs = As + 128 * 32;                  // 8 KB
    unsigned short* Cs = Bs + 128 * 32;                  // 33.8 KB [128][132]
    const int b = blockIdx.x - 64;
    const int w = tid >> 6, l = tid & 63, lo = l & 15, hi = l >> 4;
    const int wr = w >> 1, wc = w & 1;
    const int srow = tid >> 2;
    const int scol = (tid & 3) * 8;
    for (int i = 0; i < 16; ++i) {
      int tau = i * 192 + b;
      int mt = tau / 24, nt = tau - mt * 24;
      int m0 = mt * 128, n0 = nt * 128;
      f32x4 acc[4][4];
#pragma unroll
      for (int ii = 0; ii < 4; ii++)
#pragma unroll
        for (int j = 0; j < 4; j++) acc[ii][j] = (f32x4){0.f, 0.f, 0.f, 0.f};
      for (int kt = 0; kt < 32; kt++) {
        int k0 = kt * 32;
        __syncthreads();
        gload_lds16(Xb + (size_t)(m0 + srow) * 1024 + k0 + scol, As + srow * 32 + scol);
        gload_lds16(Xb + (size_t)(m0 + 64 + srow) * 1024 + k0 + scol, As + (64 + srow) * 32 + scol);
        gload_lds16(Wihb + (size_t)(n0 + srow) * 1024 + k0 + scol, Bs + srow * 32 + scol);
        gload_lds16(Wihb + (size_t)(n0 + 64 + srow) * 1024 + k0 + scol, Bs + (64 + srow) * 32 + scol);
        asm volatile("s_waitcnt vmcnt(0)" ::: "memory");
        __syncthreads();
        short8 a[4], bb[4];
#pragma unroll
        for (int ii = 0; ii < 4; ii++) a[ii] = *(const short8*)(As + (wr * 64 + ii * 16 + lo) * 32 + hi * 8);
#pragma unroll
        for (int ii = 0; ii < 4; ii++) bb[ii] = *(const short8*)(Bs + (wc * 64 + ii * 16 + lo) * 32 + hi * 8);
#pragma unroll
        for (int ii = 0; ii < 4; ii++)
#pragma unroll
          for (int j = 0; j < 4; j++) acc[ii][j] = mfma16(a[ii], bb[j], acc[ii][j]);
      }
      // stage C tile (E-folded bf16) into LDS
#pragma unroll
      for (int ii = 0; ii < 4; ii++)
#pragma unroll
        for (int j = 0; j < 4; j++)
#pragma unroll
          for (int e = 0; e < 4; e++) {
            int r = wr * 64 + ii * 16 + hi * 4 + e;
            int c = wc * 64 + j * 16 + lo;
            float v = acc[ii][j][e] + E[(size_t)((m0 + r) & 63) * G3 + n0 + c];
            Cs[r * 132 + c] = f2bf(v);
          }
      __syncthreads();
      // coalesced bypass stores: thread -> row tid>>1, half (tid&1)*64
      {
        int rr = tid >> 1;
        int cc = (tid & 1) * 64;
        unsigned short* gp = gi + (size_t)(m0 + rr) * G3 + n0 + cc;
        const unsigned short* cp = Cs + rr * 132 + cc;
#pragma unroll
        for (int q = 0; q < 8; ++q)
          mall_store16(gp + q * 8, *(const short8*)(cp + q * 8));
      }
      asm volatile("s_waitcnt vmcnt(0)" ::: "memory");
      __syncthreads();   // all waves' stores at MALL; Cs reusable
      if (tid == 0)
        __hip_atomic_fetch_add(&ready[mt * 16], 1u, __ATOMIC_RELAXED, __HIP_MEMORY_SCOPE_AGENT);
    }
    return;
  }

  // ================= recurrence role (blocks 0-63) =================
  unsigned short* wlds = (unsigned short*)smem;   // 96 KB [96 frag=kk*3+s][64 lane][8]
  float* h0f = (float*)(smem + 98304);            // [2][16]

  const int cs = blockIdx.x, j0 = cs * 16;
  const int w = tid >> 6, l = tid & 63, lo = l & 15, hi = l >> 4;
  const int rowbase = w * 32;
  const int col = j0 + lo;

  float bhhn = 0.f;
  float hA[4] = {0,0,0,0}, hB[4] = {0,0,0,0};
  int lenA[4] = {0,0,0,0}, lenB[4] = {0,0,0,0};

  if (tid < 128) {
#pragma unroll
    for (int k2 = 0; k2 < 16; ++k2) {
      int kk = w * 16 + k2;
#pragma unroll
      for (int s = 0; s < 3; ++s) {
        int f = kk * 3 + s;
        short8 v = *(const short8*)(Whhb + (size_t)(s * 1024 + j0 + lo) * 1024 + kk * 32 + hi * 8);
        ((short8*)wlds)[f * 64 + l] = v;
      }
    }
    bhhn = b_hh[2048 + col];
#pragma unroll
    for (int j = 0; j < 4; ++j) {
      int rA = rowbase + hi * 4 + j, rB = rA + 16;
      hA[j] = h0[(size_t)rA * 1024 + col]; lenA[j] = length[rA];
      hB[j] = h0[(size_t)rB * 1024 + col]; lenB[j] = length[rB];
    }
    unsigned short* dst = hbuf + (size_t)cs * 1024;
#pragma unroll
    for (int j = 0; j < 4; ++j) {
      unsigned int mA = f2bf(hA[j]), mB = f2bf(hB[j]);
      unsigned int oA = __shfl_xor(mA, 1, 64), oB = __shfl_xor(mB, 1, 64);
      if (!(lo & 1)) {
        int rr = rowbase + hi * 4 + j;
        __hip_atomic_store((unsigned int*)(dst + rr * 16 + lo), mA | (oA << 16),
                           __ATOMIC_RELAXED, __HIP_MEMORY_SCOPE_AGENT);
        __hip_atomic_store((unsigned int*)(dst + (rr + 16) * 16 + lo), mB | (oB << 16),
                           __ATOMIC_RELAXED, __HIP_MEMORY_SCOPE_AGENT);
      }
    }
    if (w == 0 && hi == 0) h0f[lo] = hA[0];
  }
  __syncthreads();          // ALL 256 threads arrive exactly once
  if (tid >= 128) return;   // extra threads exit AFTER the barrier
  asm volatile("s_waitcnt vmcnt(0)" ::: "memory");
  if (l == 0)
    __hip_atomic_store(&seq[(cs * 2 + w) * 16], 1u, __ATOMIC_RELAXED, __HIP_MEMORY_SCOPE_AGENT);

#define POLL_READY(MT)                                                                  \
  {                                                                                     \
    const unsigned int* rp = ready + (size_t)(MT) * 16;                                 \
    for (;;) {                                                                          \
      unsigned int v = __hip_atomic_load(rp, __ATOMIC_RELAXED, __HIP_MEMORY_SCOPE_AGENT);\
      if (v >= 24u) break;                                                              \
      __builtin_amdgcn_s_sleep(1);                                                      \
    }                                                                                   \
    asm volatile("" ::: "memory");                                                      \
    __builtin_amdgcn_sched_barrier(0);                                                  \
  }

  unsigned short gir[24];
  POLL_READY(0);
#pragma unroll
  for (int r2 = 0; r2 < 2; ++r2)
#pragma unroll
    for (int s = 0; s < 3; ++s)
#pragma unroll
      for (int j = 0; j < 4; ++j)
        gir[(r2 * 3 + s) * 4 + j] =
            gi[(size_t)(rowbase + r2 * 16 + hi * 4 + j) * G3 + s * 1024 + col];

#define ISSUE(c, X)                                                                    \
  _Pragma("unroll") for (int k2 = 0; k2 < 8; ++k2) {                                   \
    int kk = (c) * 8 + k2;                                                             \
    size_t cb = (size_t)(kk * 2 + (hi >> 1));                                          \
    X[k2 * 2 + 0] = mall_load16(base + (cb * 64 + rowbase + lo) * 16 + (hi & 1) * 8);  \
    X[k2 * 2 + 1] = mall_load16(base + (cb * 64 + rowbase + 16 + lo) * 16 + (hi & 1) * 8); \
  }
#define WAITV(N)                                                                       \
  asm volatile("s_waitcnt vmcnt(" #N ")" ::: "memory");                                \
  __builtin_amdgcn_sched_barrier(0)
#define CRUNCH(c, X)                                                                   \
  _Pragma("unroll") for (int k2 = 0; k2 < 8; ++k2) {                                   \
    int kk = (c) * 8 + k2;                                                             \
    const short8* wf = ((const short8*)wlds) + (size_t)(kk * 3) * 64 + l;              \
    short8 b0 = wf[0], b1 = wf[64], b2 = wf[128];                                      \
    a00 = mfma16(X[k2 * 2 + 0], b0, a00);                                              \
    a01 = mfma16(X[k2 * 2 + 0], b1, a01);                                              \
    a02 = mfma16(X[k2 * 2 + 0], b2, a02);                                              \
    a10 = mfma16(X[k2 * 2 + 1], b0, a10);                                              \
    a11 = mfma16(X[k2 * 2 + 1], b1, a11);                                              \
    a12 = mfma16(X[k2 * 2 + 1], b2, a12);                                              \
  }

  for (int t = 0; t < TT; ++t) {
    {
      const unsigned int* sp0 = seq + (size_t)(2 * l) * 16;
      const unsigned int* sp1 = sp0 + 16;
      unsigned int tgt = (unsigned int)(t + 1);
      for (;;) {
        unsigned int v0 = __hip_atomic_load(sp0, __ATOMIC_RELAXED, __HIP_MEMORY_SCOPE_AGENT);
        unsigned int v1 = __hip_atomic_load(sp1, __ATOMIC_RELAXED, __HIP_MEMORY_SCOPE_AGENT);
        if (__all((v0 >= tgt) && (v1 >= tgt))) break;
        __builtin_amdgcn_s_sleep(1);
      }
    }
    const unsigned short* base = hbuf + ((size_t)(t & 1) * 64) * 1024;
    f32x4 a00 = {0.f, 0.f, 0.f, 0.f}, a01 = a00, a02 = a00, a10 = a00, a11 = a00, a12 = a00;
    {
      short8 XA[16], XB[16];
      ISSUE(0, XA);
      ISSUE(1, XB);
      WAITV(16);
      CRUNCH(0, XA);
      ISSUE(2, XA);
      WAITV(16);
      CRUNCH(1, XB);
      ISSUE(3, XB);
      WAITV(16);
      CRUNCH(2, XA);
      WAITV(0);
      CRUNCH(3, XB);
    }
    float h0p = (w == 0) ? __shfl(hA[0], lo, 64) : h0f[(t & 1) * 16 + lo];
    float rA[4], rB[4];
#pragma unroll
    for (int j = 0; j < 4; ++j) {
      float R = a00[j] + bf2f(gir[0 * 4 + j]);
      float I = a01[j] + bf2f(gir[1 * 4 + j]);
      float rg = 1.f / (1.f + __expf(-R));
      float ig = 1.f / (1.f + __expf(-I));
      float nx = bf2f(gir[2 * 4 + j]) + rg * (a02[j] + bhhn);
      nx = fminf(15.f, fmaxf(-15.f, nx));
      float e2 = __expf(2.f * nx);
      float ng = (e2 - 1.f) / (e2 + 1.f);
      float hy = ng + ig * (hA[j] - ng);
      rA[j] = (t < lenA[j]) ? hy : h0p;
    }
#pragma unroll
    for (int j = 0; j < 4; ++j) {
      float R = a10[j] + bf2f(gir[(3 + 0) * 4 + j]);
      float I = a11[j] + bf2f(gir[(3 + 1) * 4 + j]);
      float rg = 1.f / (1.f + __expf(-R));
      float ig = 1.f / (1.f + __expf(-I));
      float nx = bf2f(gir[(3 + 2) * 4 + j]) + rg * (a12[j] + bhhn);
      nx = fminf(15.f, fmaxf(-15.f, nx));
      float e2 = __expf(2.f * nx);
      float ng = (e2 - 1.f) / (e2 + 1.f);
      float hy = ng + ig * (hB[j] - ng);
      rB[j] = (t < lenB[j]) ? hy : h0p;
    }
#pragma unroll
    for (int j = 0; j < 4; ++j) { hA[j] = rA[j]; hB[j] = rB[j]; }
    if (t < TT - 1) {
      unsigned short* dst = hbuf + ((size_t)((t + 1) & 1) * 64 + cs) * 1024;
#pragma unroll
      for (int j = 0; j < 4; ++j) {
        unsigned int mA = f2bf(hA[j]), mB = f2bf(hB[j]);
        unsigned int oA = __shfl_xor(mA, 1, 64), oB = __shfl_xor(mB, 1, 64);
        if (!(lo & 1)) {
          int rr = rowbase + hi * 4 + j;
          __hip_atomic_store((unsigned int*)(dst + rr * 16 + lo), mA | (oA << 16),
                             __ATOMIC_RELAXED, __HIP_MEMORY_SCOPE_AGENT);
          __hip_atomic_store((unsigned int*)(dst + (rr + 16) * 16 + lo), mB | (oB << 16),
                             __ATOMIC_RELAXED, __HIP_MEMORY_SCOPE_AGENT);
        }
      }
      if (w == 0 && hi == 0) h0f[((t + 1) & 1) * 16 + lo] = hA[0];
      asm volatile("s_waitcnt vmcnt(0) lgkmcnt(0)" ::: "memory");
      if (l == 0)
        __hip_atomic_store(&seq[(cs * 2 + w) * 16], (unsigned int)(t + 2),
                           __ATOMIC_RELAXED, __HIP_MEMORY_SCOPE_AGENT);
#pragma unroll
      for (int j = 0; j < 4; ++j) {
        int rr = rowbase + hi * 4 + j;
        out[(size_t)t * (BB * HH) + (size_t)rr * 1024 + col] = rA[j];
        out[(size_t)t * (BB * HH) + (size_t)(rr + 16) * 1024 + col] = rB[j];
      }
      if (((t + 1) & 1) == 0) { POLL_READY((t + 1) >> 1); }
      const unsigned short* gb = gi + (size_t)(t + 1) * 64 * G3;
#pragma unroll
      for (int r2 = 0; r2 < 2; ++r2)
#pragma unroll
        for (int s = 0; s < 3; ++s)
#pragma unroll
          for (int j = 0; j < 4; ++j)
            gir[(r2 * 3 + s) * 4 + j] =
                gb[(size_t)(rowbase + r2 * 16 + hi * 4 + j) * G3 + s * 1024 + col];
    } else {
#pragma unroll
      for (int j = 0; j < 4; ++j) {
        int rr = rowbase + hi * 4 + j;
        out[(size_t)t * (BB * HH) + (size_t)rr * 1024 + col] = rA[j];
        out[(size_t)t * (BB * HH) + (size_t)(rr + 16) * 1024 + col] = rB[j];
        hn[(size_t)rr * 1024 + col] = rA[j];
        hn[(size_t)(rr + 16) * 1024 + col] = rB[j];
      }
    }
  }
#undef ISSUE
#undef WAITV
#undef CRUNCH
#undef POLL_READY
}

// ---------------- host ----------------
extern "C" void kernel_launch(void* const* d_in, const int* in_sizes, int n_in,
                              void* d_out, int out_size, void* d_ws, size_t ws_size,
                              hipStream_t stream) {
  const float* input_ = (const float*)d_in[0];
  const int* length   = (const int*)d_in[1];
  const float* h0     = (const float*)d_in[2];
  const float* cj     = (const float*)d_in[3];
  const float* he     = (const float*)d_in[4];
  const float* w_ih   = (const float*)d_in[5];
  const float* w_hh   = (const float*)d_in[6];
  const float* w_ch   = (const float*)d_in[7];
  const float* w_zh   = (const float*)d_in[8];
  const float* b_ih   = (const float*)d_in[9];
  const float* b_hh   = (const float*)d_in[10];
  const float* b_ch   = (const float*)d_in[11];
  const float* b_zh   = (const float*)d_in[12];

  char* ws = (char*)d_ws;
  const size_t OFF_SEQ   = 0;               // 16 KB region
  const size_t OFF_READY = 16384;           // 8 KB region
  const size_t OFF_HBUF  = 32768;           // 256 KB
  const size_t OFF_XB    = 524288;
  const size_t OFF_WIHB  = OFF_XB + 33554432ull;
  const size_t OFF_WHHB  = OFF_WIHB + 6291456ull;
  const size_t OFF_WCHB  = OFF_WHHB + 6291456ull;
  const size_t OFF_WZHB  = OFF_WCHB + 6291456ull;
  const size_t OFF_CJB   = OFF_WZHB + 6291456ull;
  const size_t OFF_HEB   = OFF_CJB + 131072ull;
  const size_t OFF_E     = OFF_HEB + 131072ull;
  const size_t OFF_GI    = OFF_E + 786432ull;

  unsigned int* seq     = (unsigned int*)(ws + OFF_SEQ);
  unsigned int* ready   = (unsigned int*)(ws + OFF_READY);
  unsigned short* hbuf  = (unsigned short*)(ws + OFF_HBUF);
  unsigned short* Xb    = (unsigned short*)(ws + OFF_XB);
  unsigned short* Wihb  = (unsigned short*)(ws + OFF_WIHB);
  unsigned short* Whhb  = (unsigned short*)(ws + OFF_WHHB);
  unsigned short* Wchb  = (unsigned short*)(ws + OFF_WCHB);
  unsigned short* Wzhb  = (unsigned short*)(ws + OFF_WZHB);
  unsigned short* cjb   = (unsigned short*)(ws + OFF_CJB);
  unsigned short* heb   = (unsigned short*)(ws + OFF_HEB);
  float* E              = (float*)(ws + OFF_E);
  unsigned short* gi    = (unsigned short*)(ws + OFF_GI);

  float* out = (float*)d_out;
  float* hn  = out + 16777216;   // T*B*H

  hipFuncSetAttribute((const void*)k_fused, hipFuncAttributeMaxDynamicSharedMemorySize, 98432);

  hipMemsetAsync(ws, 0, 24576, stream);   // seq + ready
  k_cvt_bf16<<<2048, 256, 0, stream>>>(input_, Xb, 16777216 / 4);
  k_cvt_bf16<<<1024, 256, 0, stream>>>(w_ih, Wihb, 3145728 / 4);
  k_cvt_bf16<<<1024, 256, 0, stream>>>(w_hh, Whhb, 3145728 / 4);
  k_cvt_bf16<<<1024, 256, 0, stream>>>(w_ch, Wchb, 3145728 / 4);
  k_cvt_bf16<<<1024, 256, 0, stream>>>(w_zh, Wzhb, 3145728 / 4);
  k_cvt_bf16<<<64, 256, 0, stream>>>(cj, cjb, 65536 / 4);
  k_cvt_bf16<<<64, 256, 0, stream>>>(he, heb, 65536 / 4);
  k_ctx<<<192, 256, 0, stream>>>(cjb, heb, Wchb, Wzhb, b_ih, b_hh, b_ch, b_zh, E);
  k_fused<<<256, 256, 98432, stream>>>(Xb, Wihb, E, gi, Whhb, b_hh, h0, length,
                                       hbuf, out, hn, seq, ready);
}

// Round 19
// 1408.373 us; speedup vs baseline: 1.6248x; 1.0172x over previous
//
#include <hip/hip_runtime.h>
#include <stdint.h>

#define TT 256
#define BB 64
#define DD 1024
#define HH 1024
#define G3 3072

typedef unsigned long long ull;
typedef __attribute__((ext_vector_type(8))) short short8;
typedef __attribute__((ext_vector_type(4))) float f32x4;

__device__ __forceinline__ unsigned short f2bf(float f) {
  union { float f; unsigned int i; } v; v.f = f;
  unsigned int x = v.i;
  return (unsigned short)((x + 0x7fffu + ((x >> 16) & 1u)) >> 16);
}
__device__ __forceinline__ float bf2f(unsigned short u) {
  union { unsigned int i; float f; } v; v.i = ((unsigned int)u) << 16; return v.f;
}
__device__ __forceinline__ f32x4 mfma16(short8 a, short8 b, f32x4 c) {
  return __builtin_amdgcn_mfma_f32_16x16x32_bf16(a, b, c, 0, 0, 0);
}
__device__ __forceinline__ void gload_lds16(const void* g, void* l) {
  __builtin_amdgcn_global_load_lds((const __attribute__((address_space(1))) void*)g,
                                   (__attribute__((address_space(3))) void*)l,
                                   16, 0, 0);
}
// 16B cache-bypass load (coherent from MALL). Reads are seq-gated.
// NOTE: raw asm load => compiler does NOT insert s_waitcnt; callers MUST
// wait with explicit counted vmcnt before consuming the result (rule #18).
__device__ __forceinline__ short8 mall_load16(const unsigned short* p) {
  short8 r;
  asm volatile("global_load_dwordx4 %0, %1, off sc0 sc1" : "=v"(r) : "v"(p));
  return r;
}

// ---------------- f32 -> bf16 convert (vectorized) ----------------
__global__ void k_cvt_bf16(const float* __restrict__ in, unsigned short* __restrict__ out, int n4) {
  int i = blockIdx.x * blockDim.x + threadIdx.x;
  int stride = gridDim.x * blockDim.x;
  for (; i < n4; i += stride) {
    float4 v = ((const float4*)in)[i];
    ushort4 o;
    o.x = f2bf(v.x); o.y = f2bf(v.y); o.z = f2bf(v.z); o.w = f2bf(v.w);
    ((ushort4*)out)[i] = o;
  }
}

// ---------------- context projections + bias fold: E[64][3072] ----------------
__global__ __launch_bounds__(256) void k_ctx(
    const unsigned short* __restrict__ cjb, const unsigned short* __restrict__ heb,
    const unsigned short* __restrict__ Wchb, const unsigned short* __restrict__ Wzhb,
    const float* __restrict__ b_ih, const float* __restrict__ b_hh,
    const float* __restrict__ b_ch, const float* __restrict__ b_zh,
    float* __restrict__ E) {
  __shared__ f32x4 red[4][4][64];   // 16 KB
  int n0 = blockIdx.x * 16;         // 192 blocks
  int tid = threadIdx.x;
  int w = tid >> 6, l = tid & 63, lo = l & 15, hi = l >> 4;
  f32x4 acc[4];
#pragma unroll
  for (int r = 0; r < 4; r++) acc[r] = (f32x4){0.f, 0.f, 0.f, 0.f};
#pragma unroll 4
  for (int kk = 0; kk < 16; kk++) {
    int k = w * 512 + kk * 32;
    const unsigned short* Asrc = (k < 1024) ? cjb : heb;
    const unsigned short* Bsrc = (k < 1024) ? Wchb : Wzhb;
    int kw = (k < 1024) ? k : (k - 1024);
    int kof = kw + hi * 8;
    short8 bf = *(const short8*)(Bsrc + (size_t)(n0 + lo) * 1024 + kof);
#pragma unroll
    for (int r = 0; r < 4; r++) {
      short8 af = *(const short8*)(Asrc + (size_t)(r * 16 + lo) * 1024 + kof);
      acc[r] = mfma16(af, bf, acc[r]);
    }
  }
#pragma unroll
  for (int r = 0; r < 4; r++) red[w][r][l] = acc[r];
  __syncthreads();
  f32x4 s = red[0][w][l];
#pragma unroll
  for (int w2 = 1; w2 < 4; w2++) {
    f32x4 p = red[w2][w][l];
    s[0] += p[0]; s[1] += p[1]; s[2] += p[2]; s[3] += p[3];
  }
  int g = n0 + lo;
  float bias = b_ih[g] + b_ch[g] + b_zh[g] + ((g < 2048) ? b_hh[g] : 0.0f);
#pragma unroll
  for (int j = 0; j < 4; j++) {
    int b = w * 16 + hi * 4 + j;
    E[(size_t)b * G3 + g] = s[j] + bias;
  }
}

// ---------------- gi GEMM + E fold: giE[t*64+b][g] = X@Wih^T + E[b][g] (bf16) --------
__global__ __launch_bounds__(256) void k_gemm_gi(
    const unsigned short* __restrict__ Xb,   // [16384][1024] bf16
    const unsigned short* __restrict__ Wb,   // [3072][1024] bf16
    const float* __restrict__ E,             // [64][3072] f32
    unsigned short* __restrict__ gi) {       // [16384][3072] bf16
  __shared__ unsigned short As[128 * 32];
  __shared__ unsigned short Bs[128 * 32];
  int bid = blockIdx.x;
  int mt = bid & 127;
  int nt = bid >> 7;
  int m0 = mt * 128, n0 = nt * 128;
  int tid = threadIdx.x;
  int w = tid >> 6, l = tid & 63, lo = l & 15, hi = l >> 4;
  int wr = w >> 1, wc = w & 1;
  f32x4 acc[4][4];
#pragma unroll
  for (int i = 0; i < 4; i++)
#pragma unroll
    for (int j = 0; j < 4; j++) acc[i][j] = (f32x4){0.f, 0.f, 0.f, 0.f};
  int srow = tid >> 2;
  int scol = (tid & 3) * 8;
  for (int kt = 0; kt < 32; kt++) {
    int k0 = kt * 32;
    __syncthreads();
    gload_lds16(Xb + (size_t)(m0 + srow) * 1024 + k0 + scol, As + srow * 32 + scol);
    gload_lds16(Xb + (size_t)(m0 + 64 + srow) * 1024 + k0 + scol, As + (64 + srow) * 32 + scol);
    gload_lds16(Wb + (size_t)(n0 + srow) * 1024 + k0 + scol, Bs + srow * 32 + scol);
    gload_lds16(Wb + (size_t)(n0 + 64 + srow) * 1024 + k0 + scol, Bs + (64 + srow) * 32 + scol);
    asm volatile("s_waitcnt vmcnt(0)" ::: "memory");
    __syncthreads();
    short8 a[4], b[4];
#pragma unroll
    for (int i = 0; i < 4; i++) a[i] = *(const short8*)(As + (wr * 64 + i * 16 + lo) * 32 + hi * 8);
#pragma unroll
    for (int i = 0; i < 4; i++) b[i] = *(const short8*)(Bs + (wc * 64 + i * 16 + lo) * 32 + hi * 8);
#pragma unroll
    for (int i = 0; i < 4; i++)
#pragma unroll
      for (int j = 0; j < 4; j++) acc[i][j] = mfma16(a[i], b[j], acc[i][j]);
  }
#pragma unroll
  for (int i = 0; i < 4; i++)
#pragma unroll
    for (int j = 0; j < 4; j++)
#pragma unroll
      for (int e = 0; e < 4; e++) {
        int r = m0 + wr * 64 + i * 16 + hi * 4 + e;
        int c = n0 + wc * 64 + j * 16 + lo;
        float v = acc[i][j][e] + E[(size_t)(r & 63) * G3 + c];
        gi[(size_t)r * G3 + c] = f2bf(v);
      }
}

// ---------------- persistent recurrence kernel (v11 final) ------
// 64 wgs x 128 thr (2 waves). wg cs owns h cols [cs*16,+16). Wave w owns rows
// [w*32,+32) x 16 cols x FULL K=1024 -> no cross-wave reduce, NO barriers in the
// 256-step loop. Whh in LDS (96 KB), B-frags reused across both row-tiles.
// A loads double-buffered (16-frag chunks) with COUNTED vmcnt waits +
// sched_barrier(0) fences (rule #18). Poll's compiler-inserted vmcnt(0) drains
// stragglers -> counts are exact.
__global__ __launch_bounds__(128) void k_rnn(
    const unsigned short* __restrict__ giE,   // [256*64][3072] bf16 (incl E)
    const unsigned short* __restrict__ Whhb,  // [3072][1024] bf16
    const float* __restrict__ b_hh,
    const float* __restrict__ h0,
    const int* __restrict__ length,
    unsigned short* __restrict__ hbuf,        // [2][64][64][16] ushort
    float* __restrict__ out,                  // [256][64][1024] f32
    float* __restrict__ hn,                   // [64][1024] f32
    unsigned int* __restrict__ seq) {         // [128] words, 64B-spaced
  extern __shared__ char smem[];
  unsigned short* wlds = (unsigned short*)smem;   // 96 KB [96 frag=kk*3+s][64 lane][8]
  float* h0f = (float*)(smem + 98304);            // [2][16]

  const int cs = blockIdx.x, j0 = cs * 16;
  const int tid = threadIdx.x;
  const int w = tid >> 6, l = tid & 63, lo = l & 15, hi = l >> 4;
  const int rowbase = w * 32;
  const int col = j0 + lo;

  // ---- weight preload: wave w loads kk in [w*16, w*16+16) ----
#pragma unroll
  for (int k2 = 0; k2 < 16; ++k2) {
    int kk = w * 16 + k2;
#pragma unroll
    for (int s = 0; s < 3; ++s) {
      int f = kk * 3 + s;
      short8 v = *(const short8*)(Whhb + (size_t)(s * 1024 + j0 + lo) * 1024 + kk * 32 + hi * 8);
      ((short8*)wlds)[f * 64 + l] = v;
    }
  }
  const float bhhn = b_hh[2048 + col];
  float hA[4], hB[4];
  int lenA[4], lenB[4];
#pragma unroll
  for (int j = 0; j < 4; ++j) {
    int rA = rowbase + hi * 4 + j, rB = rA + 16;
    hA[j] = h0[(size_t)rA * 1024 + col]; lenA[j] = length[rA];
    hB[j] = h0[(size_t)rB * 1024 + col]; lenB[j] = length[rB];
  }
  // ---- publish h(0) into slot 0 ----
  {
    unsigned short* dst = hbuf + (size_t)cs * 1024;
#pragma unroll
    for (int j = 0; j < 4; ++j) {
      unsigned int mA = f2bf(hA[j]), mB = f2bf(hB[j]);
      unsigned int oA = __shfl_xor(mA, 1, 64), oB = __shfl_xor(mB, 1, 64);
      if (!(lo & 1)) {
        int rr = rowbase + hi * 4 + j;
        __hip_atomic_store((unsigned int*)(dst + rr * 16 + lo), mA | (oA << 16),
                           __ATOMIC_RELAXED, __HIP_MEMORY_SCOPE_AGENT);
        __hip_atomic_store((unsigned int*)(dst + (rr + 16) * 16 + lo), mB | (oB << 16),
                           __ATOMIC_RELAXED, __HIP_MEMORY_SCOPE_AGENT);
      }
    }
  }
  if (w == 0 && hi == 0) h0f[lo] = hA[0];   // exact f32 h(0)[0][col]
  __syncthreads();   // init only: wlds + h0f ready
  asm volatile("s_waitcnt vmcnt(0)" ::: "memory");
  if (l == 0)
    __hip_atomic_store(&seq[(cs * 2 + w) * 16], 1u, __ATOMIC_RELAXED, __HIP_MEMORY_SCOPE_AGENT);
  // ---- gir prefetch for t=0: 24 ushort (2 rt x 3 s x 4 j) ----
  unsigned short gir[24];
#pragma unroll
  for (int r2 = 0; r2 < 2; ++r2)
#pragma unroll
    for (int s = 0; s < 3; ++s)
#pragma unroll
      for (int j = 0; j < 4; ++j)
        gir[(r2 * 3 + s) * 4 + j] =
            giE[(size_t)(rowbase + r2 * 16 + hi * 4 + j) * G3 + s * 1024 + col];

#define ISSUE(c, X)                                                                    \
  _Pragma("unroll") for (int k2 = 0; k2 < 8; ++k2) {                                   \
    int kk = (c) * 8 + k2;                                                             \
    size_t cb = (size_t)(kk * 2 + (hi >> 1));                                          \
    X[k2 * 2 + 0] = mall_load16(base + (cb * 64 + rowbase + lo) * 16 + (hi & 1) * 8);  \
    X[k2 * 2 + 1] = mall_load16(base + (cb * 64 + rowbase + 16 + lo) * 16 + (hi & 1) * 8); \
  }
#define WAITV(N)                                                                       \
  asm volatile("s_waitcnt vmcnt(" #N ")" ::: "memory");                                \
  __builtin_amdgcn_sched_barrier(0)
#define CRUNCH(c, X)                                                                   \
  _Pragma("unroll") for (int k2 = 0; k2 < 8; ++k2) {                                   \
    int kk = (c) * 8 + k2;                                                             \
    const short8* wf = ((const short8*)wlds) + (size_t)(kk * 3) * 64 + l;              \
    short8 b0 = wf[0], b1 = wf[64], b2 = wf[128];                                      \
    a00 = mfma16(X[k2 * 2 + 0], b0, a00);                                              \
    a01 = mfma16(X[k2 * 2 + 0], b1, a01);                                              \
    a02 = mfma16(X[k2 * 2 + 0], b2, a02);                                              \
    a10 = mfma16(X[k2 * 2 + 1], b0, a10);                                              \
    a11 = mfma16(X[k2 * 2 + 1], b1, a11);                                              \
    a12 = mfma16(X[k2 * 2 + 1], b2, a12);                                              \
  }

  for (int t = 0; t < TT; ++t) {
    // ---- poll all 128 producer words (2 per lane); compiler's vmcnt(0) before
    // the compare drains all prior vmem -> vmcnt baseline 0 after this ----
    {
      const unsigned int* sp0 = seq + (size_t)(2 * l) * 16;
      const unsigned int* sp1 = sp0 + 16;
      unsigned int tgt = (unsigned int)(t + 1);
      for (;;) {
        unsigned int v0 = __hip_atomic_load(sp0, __ATOMIC_RELAXED, __HIP_MEMORY_SCOPE_AGENT);
        unsigned int v1 = __hip_atomic_load(sp1, __ATOMIC_RELAXED, __HIP_MEMORY_SCOPE_AGENT);
        if (__all((v0 >= tgt) && (v1 >= tgt))) break;
        __builtin_amdgcn_s_sleep(1);
      }
    }
    // ---- chunked A loads + MFMA (full K for 2 row-tiles), counted waits ----
    const unsigned short* base = hbuf + ((size_t)(t & 1) * 64) * 1024;
    f32x4 a00 = {0.f, 0.f, 0.f, 0.f}, a01 = a00, a02 = a00, a10 = a00, a11 = a00, a12 = a00;
    {
      short8 XA[16], XB[16];
      ISSUE(0, XA);        // 16 outstanding
      ISSUE(1, XB);        // 32 outstanding
      WAITV(16);           // chunk 0 landed
      CRUNCH(0, XA);
      ISSUE(2, XA);        // <=32 outstanding
      WAITV(16);           // chunk 1 landed
      CRUNCH(1, XB);
      ISSUE(3, XB);        // <=32 outstanding
      WAITV(16);           // chunk 2 landed
      CRUNCH(2, XA);
      WAITV(0);            // chunk 3 landed
      CRUNCH(3, XB);
    }
    // ---- gates for 8 rows/lane ----
    float h0p = (w == 0) ? __shfl(hA[0], lo, 64) : h0f[(t & 1) * 16 + lo];
    float rA[4], rB[4];
#pragma unroll
    for (int j = 0; j < 4; ++j) {
      float R = a00[j] + bf2f(gir[0 * 4 + j]);
      float I = a01[j] + bf2f(gir[1 * 4 + j]);
      float rg = 1.f / (1.f + __expf(-R));
      float ig = 1.f / (1.f + __expf(-I));
      float nx = bf2f(gir[2 * 4 + j]) + rg * (a02[j] + bhhn);
      nx = fminf(15.f, fmaxf(-15.f, nx));
      float e2 = __expf(2.f * nx);
      float ng = (e2 - 1.f) / (e2 + 1.f);
      float hy = ng + ig * (hA[j] - ng);
      rA[j] = (t < lenA[j]) ? hy : h0p;
    }
#pragma unroll
    for (int j = 0; j < 4; ++j) {
      float R = a10[j] + bf2f(gir[(3 + 0) * 4 + j]);
      float I = a11[j] + bf2f(gir[(3 + 1) * 4 + j]);
      float rg = 1.f / (1.f + __expf(-R));
      float ig = 1.f / (1.f + __expf(-I));
      float nx = bf2f(gir[(3 + 2) * 4 + j]) + rg * (a12[j] + bhhn);
      nx = fminf(15.f, fmaxf(-15.f, nx));
      float e2 = __expf(2.f * nx);
      float ng = (e2 - 1.f) / (e2 + 1.f);
      float hy = ng + ig * (hB[j] - ng);
      rB[j] = (t < lenB[j]) ? hy : h0p;
    }
#pragma unroll
    for (int j = 0; j < 4; ++j) { hA[j] = rA[j]; hB[j] = rB[j]; }
    if (t < TT - 1) {
      // ---- publish h(t+1) + h0f + signal ----
      unsigned short* dst = hbuf + ((size_t)((t + 1) & 1) * 64 + cs) * 1024;
#pragma unroll
      for (int j = 0; j < 4; ++j) {
        unsigned int mA = f2bf(hA[j]), mB = f2bf(hB[j]);
        unsigned int oA = __shfl_xor(mA, 1, 64), oB = __shfl_xor(mB, 1, 64);
        if (!(lo & 1)) {
          int rr = rowbase + hi * 4 + j;
          __hip_atomic_store((unsigned int*)(dst + rr * 16 + lo), mA | (oA << 16),
                             __ATOMIC_RELAXED, __HIP_MEMORY_SCOPE_AGENT);
          __hip_atomic_store((unsigned int*)(dst + (rr + 16) * 16 + lo), mB | (oB << 16),
                             __ATOMIC_RELAXED, __HIP_MEMORY_SCOPE_AGENT);
        }
      }
      if (w == 0 && hi == 0) h0f[((t + 1) & 1) * 16 + lo] = hA[0];
      asm volatile("s_waitcnt vmcnt(0) lgkmcnt(0)" ::: "memory");
      if (l == 0)
        __hip_atomic_store(&seq[(cs * 2 + w) * 16], (unsigned int)(t + 2),
                           __ATOMIC_RELAXED, __HIP_MEMORY_SCOPE_AGENT);
      // ---- off critical path: out(t) stores + gir(t+1) prefetch ----
#pragma unroll
      for (int j = 0; j < 4; ++j) {
        int rr = rowbase + hi * 4 + j;
        out[(size_t)t * (BB * HH) + (size_t)rr * 1024 + col] = rA[j];
        out[(size_t)t * (BB * HH) + (size_t)(rr + 16) * 1024 + col] = rB[j];
      }
      const unsigned short* gb = giE + (size_t)(t + 1) * 64 * G3;
#pragma unroll
      for (int r2 = 0; r2 < 2; ++r2)
#pragma unroll
        for (int s = 0; s < 3; ++s)
#pragma unroll
          for (int j = 0; j < 4; ++j)
            gir[(r2 * 3 + s) * 4 + j] =
                gb[(size_t)(rowbase + r2 * 16 + hi * 4 + j) * G3 + s * 1024 + col];
    } else {
      // ---- tail: out(255) + hn ----
#pragma unroll
      for (int j = 0; j < 4; ++j) {
        int rr = rowbase + hi * 4 + j;
        out[(size_t)t * (BB * HH) + (size_t)rr * 1024 + col] = rA[j];
        out[(size_t)t * (BB * HH) + (size_t)(rr + 16) * 1024 + col] = rB[j];
        hn[(size_t)rr * 1024 + col] = rA[j];
        hn[(size_t)(rr + 16) * 1024 + col] = rB[j];
      }
    }
  }
#undef ISSUE
#undef WAITV
#undef CRUNCH
}

// ---------------- host ----------------
extern "C" void kernel_launch(void* const* d_in, const int* in_sizes, int n_in,
                              void* d_out, int out_size, void* d_ws, size_t ws_size,
                              hipStream_t stream) {
  const float* input_ = (const float*)d_in[0];
  const int* length   = (const int*)d_in[1];
  const float* h0     = (const float*)d_in[2];
  const float* cj     = (const float*)d_in[3];
  const float* he     = (const float*)d_in[4];
  const float* w_ih   = (const float*)d_in[5];
  const float* w_hh   = (const float*)d_in[6];
  const float* w_ch   = (const float*)d_in[7];
  const float* w_zh   = (const float*)d_in[8];
  const float* b_ih   = (const float*)d_in[9];
  const float* b_hh   = (const float*)d_in[10];
  const float* b_ch   = (const float*)d_in[11];
  const float* b_zh   = (const float*)d_in[12];

  char* ws = (char*)d_ws;
  const size_t OFF_SEQ   = 0;               // 16 KB: 128 words, 64B-spaced
  const size_t OFF_HBUF  = 16384;           // 256 KB: [2][64][64][16] ushort
  const size_t OFF_XB    = 524288;
  const size_t OFF_WIHB  = OFF_XB + 33554432ull;
  const size_t OFF_WHHB  = OFF_WIHB + 6291456ull;
  const size_t OFF_WCHB  = OFF_WHHB + 6291456ull;
  const size_t OFF_WZHB  = OFF_WCHB + 6291456ull;
  const size_t OFF_CJB   = OFF_WZHB + 6291456ull;
  const size_t OFF_HEB   = OFF_CJB + 131072ull;
  const size_t OFF_E     = OFF_HEB + 131072ull;
  const size_t OFF_GI    = OFF_E + 786432ull;

  unsigned int* seq     = (unsigned int*)(ws + OFF_SEQ);
  unsigned short* hbuf  = (unsigned short*)(ws + OFF_HBUF);
  unsigned short* Xb    = (unsigned short*)(ws + OFF_XB);
  unsigned short* Wihb  = (unsigned short*)(ws + OFF_WIHB);
  unsigned short* Whhb  = (unsigned short*)(ws + OFF_WHHB);
  unsigned short* Wchb  = (unsigned short*)(ws + OFF_WCHB);
  unsigned short* Wzhb  = (unsigned short*)(ws + OFF_WZHB);
  unsigned short* cjb   = (unsigned short*)(ws + OFF_CJB);
  unsigned short* heb   = (unsigned short*)(ws + OFF_HEB);
  float* E              = (float*)(ws + OFF_E);
  unsigned short* gi    = (unsigned short*)(ws + OFF_GI);

  float* out = (float*)d_out;
  float* hn  = out + 16777216;   // T*B*H

  hipFuncSetAttribute((const void*)k_rnn, hipFuncAttributeMaxDynamicSharedMemorySize, 98432);

  hipMemsetAsync(seq, 0, 16384, stream);
  k_cvt_bf16<<<2048, 256, 0, stream>>>(input_, Xb, 16777216 / 4);
  k_cvt_bf16<<<1024, 256, 0, stream>>>(w_ih, Wihb, 3145728 / 4);
  k_cvt_bf16<<<1024, 256, 0, stream>>>(w_hh, Whhb, 3145728 / 4);
  k_cvt_bf16<<<1024, 256, 0, stream>>>(w_ch, Wchb, 3145728 / 4);
  k_cvt_bf16<<<1024, 256, 0, stream>>>(w_zh, Wzhb, 3145728 / 4);
  k_cvt_bf16<<<64, 256, 0, stream>>>(cj, cjb, 65536 / 4);
  k_cvt_bf16<<<64, 256, 0, stream>>>(he, heb, 65536 / 4);
  k_ctx<<<192, 256, 0, stream>>>(cjb, heb, Wchb, Wzhb, b_ih, b_hh, b_ch, b_zh, E);
  k_gemm_gi<<<3072, 256, 0, stream>>>(Xb, Wihb, E, gi);
  k_rnn<<<64, 128, 98432, stream>>>(gi, Whhb, b_hh, h0, length, hbuf, out, hn, seq);
}